// Round 1
// baseline (12534.034 us; speedup 1.0000x reference)
//
#include <hip/hip_runtime.h>
#include <hip/hip_bf16.h>
#include <math.h>

// Problem constants
#define BB 4
#define LL 1024
#define BL (BB*LL)          // 4096 tokens
#define DD 256
#define VV 32000
#define HH 4
#define DH 64
#define SS 16
#define DCC 4
#define DII 512
#define NMM 6
#define NAA 2

__device__ __forceinline__ float sp_f(float x) {        // softplus = logaddexp(x,0)
    return fmaxf(x, 0.f) + log1pf(expf(-fabsf(x)));
}
__device__ __forceinline__ float silu_f(float x) {
    return x / (1.f + expf(-x));
}

// ---------------------------------------------------------------- time feat
__global__ void feat_k(const float* __restrict__ ts, const float* __restrict__ freq,
                       const float* __restrict__ phase, float* __restrict__ feat) {
    int row = blockIdx.x, t = threadIdx.x;
    float tv = ts[row];
    int d = t & 127;
    float f = sp_f(freq[d]);
    float arg = tv * f + phase[d];
    feat[(size_t)row * DD + t] = (t < 128) ? sinf(arg) : cosf(arg);
}

// ---------------------------------------------------------------- embeddings
__global__ void embed_k(float* __restrict__ x, const int* __restrict__ ids,
                        const int* __restrict__ typ, const float* __restrict__ tok,
                        const float* __restrict__ tpe) {
    int row = blockIdx.x, t = threadIdx.x;
    x[(size_t)row * DD + t] += tok[(size_t)ids[row] * DD + t] + tpe[(size_t)typ[row] * DD + t];
}

// ---------------------------------------------------------------- layernorm (row of 256)
__global__ void ln_k(const float* __restrict__ x, const float* __restrict__ g,
                     const float* __restrict__ bbias, float* __restrict__ out) {
    __shared__ float red[8];
    int row = blockIdx.x, t = threadIdx.x;
    float v = x[(size_t)row * DD + t];
    float s = v;
    #pragma unroll
    for (int o = 32; o >= 1; o >>= 1) s += __shfl_xor(s, o);
    if ((t & 63) == 0) red[t >> 6] = s;
    __syncthreads();
    float mean = (red[0] + red[1] + red[2] + red[3]) * (1.f / 256.f);
    float d = v - mean;
    float s2 = d * d;
    #pragma unroll
    for (int o = 32; o >= 1; o >>= 1) s2 += __shfl_xor(s2, o);
    if ((t & 63) == 0) red[4 + (t >> 6)] = s2;
    __syncthreads();
    float var = (red[4] + red[5] + red[6] + red[7]) * (1.f / 256.f);
    out[(size_t)row * DD + t] = d * rsqrtf(var + 1e-5f) * g[t] + bbias[t];
}

// ---------------------------------------------------------------- generic GEMM  out = A(MxK) @ W(NxK)^T
// ACT: 0 none, 1 silu, 2 softplus
constexpr int GBM = 64, GBN = 64, GBK = 16;

template <int ACT, bool HASB, bool HASR>
__global__ __launch_bounds__(256) void gemm_k(
    const float* __restrict__ A, const float* __restrict__ W,
    const float* __restrict__ bias, const float* __restrict__ res,
    float* __restrict__ out, int M, int N, int K) {
    __shared__ float As[GBK][GBM + 1];
    __shared__ float Ws[GBK][GBN + 1];
    int tid = threadIdx.x;
    int tx = tid & 15, ty = tid >> 4;
    int bm = blockIdx.y * GBM, bn = blockIdx.x * GBN;
    int lr = tid >> 2;          // 0..63
    int lk = (tid & 3) * 4;     // 0,4,8,12
    float acc[4][4] = {};
    for (int kk = 0; kk < K; kk += GBK) {
        int r = bm + lr;
        float4 av = make_float4(0.f, 0.f, 0.f, 0.f);
        if (r < M) av = *(const float4*)(A + (size_t)r * K + kk + lk);
        As[lk + 0][lr] = av.x; As[lk + 1][lr] = av.y;
        As[lk + 2][lr] = av.z; As[lk + 3][lr] = av.w;
        int n = bn + lr;
        float4 wv = make_float4(0.f, 0.f, 0.f, 0.f);
        if (n < N) wv = *(const float4*)(W + (size_t)n * K + kk + lk);
        Ws[lk + 0][lr] = wv.x; Ws[lk + 1][lr] = wv.y;
        Ws[lk + 2][lr] = wv.z; Ws[lk + 3][lr] = wv.w;
        __syncthreads();
        #pragma unroll
        for (int k = 0; k < GBK; ++k) {
            float a[4], bv[4];
            #pragma unroll
            for (int i = 0; i < 4; ++i) a[i] = As[k][ty * 4 + i];
            #pragma unroll
            for (int j = 0; j < 4; ++j) bv[j] = Ws[k][tx * 4 + j];
            #pragma unroll
            for (int i = 0; i < 4; ++i)
                #pragma unroll
                for (int j = 0; j < 4; ++j)
                    acc[i][j] = fmaf(a[i], bv[j], acc[i][j]);
        }
        __syncthreads();
    }
    #pragma unroll
    for (int i = 0; i < 4; ++i) {
        int m = bm + ty * 4 + i;
        if (m >= M) continue;
        #pragma unroll
        for (int j = 0; j < 4; ++j) {
            int n = bn + tx * 4 + j;
            if (n >= N) continue;
            float v = acc[i][j];
            if (HASB) v += bias[n];
            if (ACT == 1) v = silu_f(v);
            if (ACT == 2) v = sp_f(v);
            if (HASR) v += res[(size_t)m * N + n];
            out[(size_t)m * N + n] = v;
        }
    }
}

// ---------------------------------------------------------------- depthwise causal conv + silu
__global__ void conv_k(const float* __restrict__ xz, const float* __restrict__ w,
                       const float* __restrict__ cb, float* __restrict__ xb) {
    int idx = blockIdx.x * blockDim.x + threadIdx.x;  // BL*DI
    int c = idx & (DII - 1);
    int row = idx >> 9;       // token index (b*L + l)
    int l = row & (LL - 1);
    int base = row - l;       // b*L
    const float* wc = w + c * DCC;
    float s = cb[c];
    #pragma unroll
    for (int j = 0; j < DCC; ++j) {
        int ll = l - (DCC - 1) + j;
        if (ll >= 0) s = fmaf(wc[j], xz[((size_t)(base + ll)) * (2 * DII) + c], s);
    }
    xb[(size_t)idx] = silu_f(s);
}

// ---------------------------------------------------------------- selective scan, thread per (b, di)
__global__ __launch_bounds__(512) void scan_k(
    const float* __restrict__ dt, const float* __restrict__ xb,
    const float* __restrict__ bc, const float* __restrict__ xz,
    const float* __restrict__ Alog, const float* __restrict__ Dp,
    float* __restrict__ y) {
    int di = threadIdx.x;
    int b = blockIdx.x;
    float A[SS];
    #pragma unroll
    for (int s = 0; s < SS; ++s) A[s] = -expf(Alog[di * SS + s]);
    float Dv = Dp[di];
    float h[SS];
    #pragma unroll
    for (int s = 0; s < SS; ++s) h[s] = 0.f;
    for (int l = 0; l < LL; ++l) {
        size_t base = (size_t)b * LL + l;
        float dtv = dt[base * DII + di];
        float xv = xb[base * DII + di];
        float zv = xz[base * (2 * DII) + DII + di];
        const float* Bt = bc + base * (2 * SS);
        float u = dtv * xv;
        float acc = 0.f;
        #pragma unroll
        for (int s = 0; s < SS; ++s) {
            float ab = expf(dtv * A[s]);
            h[s] = fmaf(ab, h[s], u * Bt[s]);
            acc = fmaf(h[s], Bt[SS + s], acc);
        }
        float yv = fmaf(Dv, xv, acc);
        y[base * DII + di] = yv * silu_f(zv);
    }
}

// ---------------------------------------------------------------- attention: one wave per (b,h,q), online softmax
__global__ __launch_bounds__(64) void attn_k(
    const float* __restrict__ qkv, const float* __restrict__ ts,
    const int* __restrict__ mask, const float* __restrict__ decay,
    float* __restrict__ out) {
    int lane = threadIdx.x;
    int q = blockIdx.x & (LL - 1);
    int h = (blockIdx.x >> 10) & (HH - 1);
    int b = blockIdx.x >> 12;
    const float* qrow = qkv + ((size_t)(b * LL + q)) * (3 * DD) + h * DH;
    float qd = qrow[lane];
    float tq = ts[b * LL + q];
    float sp = sp_f(decay[h]);
    float m = -INFINITY, den = 0.f, acc = 0.f;
    for (int k = 0; k <= q; ++k) {
        if (mask[b * LL + k] == 0) continue;
        const float* kr = qkv + ((size_t)(b * LL + k)) * (3 * DD) + DD + h * DH;
        float p = qd * kr[lane];
        #pragma unroll
        for (int o = 32; o >= 1; o >>= 1) p += __shfl_xor(p, o);
        float s = p * 0.125f - sp * fabsf(tq - ts[b * LL + k]) * (1.f / 24.f);
        float mn = fmaxf(m, s);
        float sc = expf(m - mn);      // m=-inf first iter -> 0
        float w = expf(s - mn);
        den = den * sc + w;
        const float* vr = qkv + ((size_t)(b * LL + k)) * (3 * DD) + 2 * DD + h * DH;
        acc = acc * sc + w * vr[lane];
        m = mn;
    }
    out[((size_t)(b * LL + q)) * DD + h * DH + lane] = acc / den;
}

// ---------------------------------------------------------------- readm / mort heads
__global__ __launch_bounds__(64) void heads_k(
    const float* __restrict__ xn, const float* __restrict__ re_w, const float* __restrict__ re_b,
    const float* __restrict__ mo_w, const float* __restrict__ mo_b, float* __restrict__ out) {
    int lane = threadIdx.x;
    int b = blockIdx.x & 3;
    int which = blockIdx.x >> 2;
    const float* wv = which ? mo_w : re_w;
    const float* row = xn + (size_t)b * LL * DD;  // token 0 of batch b
    float s = 0.f;
    #pragma unroll
    for (int d = 0; d < DD / 64; ++d) s = fmaf(row[lane + d * 64], wv[lane + d * 64], s);
    #pragma unroll
    for (int o = 32; o >= 1; o >>= 1) s += __shfl_xor(s, o);
    if (lane == 0) out[(size_t)VV * BL + which * 4 + b] = s + (which ? mo_b[0] : re_b[0]);
}

// ================================================================ host
extern "C" void kernel_launch(void* const* d_in, const int* in_sizes, int n_in,
                              void* d_out, int out_size, void* d_ws, size_t ws_size,
                              hipStream_t stream) {
    const int*   ids      = (const int*)  d_in[0];
    const int*   typ      = (const int*)  d_in[1];
    const float* ts       = (const float*)d_in[2];
    const int*   amask    = (const int*)  d_in[3];
    const float* tok_emb  = (const float*)d_in[4];
    const float* type_emb = (const float*)d_in[5];
    const float* te_freq  = (const float*)d_in[6];
    const float* te_phase = (const float*)d_in[7];
    const float* te_w     = (const float*)d_in[8];
    const float* te_b     = (const float*)d_in[9];
    const float* m_norm_g = (const float*)d_in[10];
    const float* m_norm_b = (const float*)d_in[11];
    const float* m_in_w   = (const float*)d_in[12];
    const float* m_conv_w = (const float*)d_in[13];
    const float* m_conv_b = (const float*)d_in[14];
    const float* m_xproj  = (const float*)d_in[15];
    const float* m_dt_w   = (const float*)d_in[16];
    const float* m_dt_b   = (const float*)d_in[17];
    const float* m_Alog   = (const float*)d_in[18];
    const float* m_D      = (const float*)d_in[19];
    const float* m_out_w  = (const float*)d_in[20];
    const float* a_norm_g = (const float*)d_in[21];
    const float* a_norm_b = (const float*)d_in[22];
    const float* a_qkv_w  = (const float*)d_in[23];
    const float* a_out_w  = (const float*)d_in[24];
    const float* a_decay  = (const float*)d_in[25];
    const float* a_ffg    = (const float*)d_in[26];
    const float* a_ffb    = (const float*)d_in[27];
    const float* a_ff1    = (const float*)d_in[28];
    const float* a_ff2    = (const float*)d_in[29];
    const float* f_g      = (const float*)d_in[30];
    const float* f_b      = (const float*)d_in[31];
    const float* lm_w     = (const float*)d_in[32];
    const float* re_w     = (const float*)d_in[33];
    const float* re_b     = (const float*)d_in[34];
    const float* mo_w     = (const float*)d_in[35];
    const float* mo_b     = (const float*)d_in[36];

    float* out = (float*)d_out;
    float* ws  = (float*)d_ws;

    // workspace layout (floats)
    float* x   = ws;                          // BL*D        = 1,048,576
    float* xn  = x  + (size_t)BL * DD;        // BL*D
    float* t1  = xn + (size_t)BL * DD;        // BL*1024 (xz / qkv / ffh)
    float* t2  = t1 + (size_t)BL * 1024;      // BL*512  (xb conv out / attn out)
    float* t3  = t2 + (size_t)BL * DII;       // BL*512  (dt)
    float* t4  = t3 + (size_t)BL * DII;       // BL*512  (scan y)
    float* t5  = t4 + (size_t)BL * DII;       // BL*32   (B,C)

    #define GEMM(ACT, Bp, Rp, Ap, Wp, Op, M, N, K)                                    \
        gemm_k<ACT, (Bp) != nullptr, (Rp) != nullptr>                                 \
            <<<dim3(((N) + GBN - 1) / GBN, ((M) + GBM - 1) / GBM), 256, 0, stream>>>( \
                Ap, Wp, Bp, Rp, Op, M, N, K)

    // NOTE: GEMM macro uses compile-time nullptr checks; pass literal nullptr or a ptr.
    // 1. time features -> xn (reused as scratch)
    feat_k<<<BL, 256, 0, stream>>>(ts, te_freq, te_phase, xn);
    // 2. enc = feat @ te_w^T + te_b  -> x
    gemm_k<0, true, false><<<dim3(DD / GBN, BL / GBM), 256, 0, stream>>>(
        xn, te_w, te_b, nullptr, x, BL, DD, DD);
    // 3. x += tok_emb[ids] + type_emb[typ]
    embed_k<<<BL, 256, 0, stream>>>(x, ids, typ, tok_emb, type_emb);

    int mi = 0, ai = 0;
    for (int i = 0; i < 8; ++i) {
        if ((i + 1) % 4 == 0) {
            // ------------- attention block ai
            ln_k<<<BL, 256, 0, stream>>>(x, a_norm_g + ai * DD, a_norm_b + ai * DD, xn);
            gemm_k<0, false, false><<<dim3((3 * DD) / GBN, BL / GBM), 256, 0, stream>>>(
                xn, a_qkv_w + (size_t)ai * 3 * DD * DD, nullptr, nullptr, t1, BL, 3 * DD, DD);
            attn_k<<<BB * HH * LL, 64, 0, stream>>>(t1, ts, amask, a_decay + ai * HH, t2);
            gemm_k<0, false, true><<<dim3(DD / GBN, BL / GBM), 256, 0, stream>>>(
                t2, a_out_w + (size_t)ai * DD * DD, nullptr, x, x, BL, DD, DD);
            ln_k<<<BL, 256, 0, stream>>>(x, a_ffg + ai * DD, a_ffb + ai * DD, xn);
            gemm_k<1, false, false><<<dim3((4 * DD) / GBN, BL / GBM), 256, 0, stream>>>(
                xn, a_ff1 + (size_t)ai * 4 * DD * DD, nullptr, nullptr, t1, BL, 4 * DD, DD);
            gemm_k<0, false, true><<<dim3(DD / GBN, BL / GBM), 256, 0, stream>>>(
                t1, a_ff2 + (size_t)ai * DD * 4 * DD, nullptr, x, x, BL, DD, 4 * DD);
            ++ai;
        } else {
            // ------------- mamba block mi
            ln_k<<<BL, 256, 0, stream>>>(x, m_norm_g + mi * DD, m_norm_b + mi * DD, xn);
            gemm_k<0, false, false><<<dim3((2 * DII) / GBN, BL / GBM), 256, 0, stream>>>(
                xn, m_in_w + (size_t)mi * 2 * DII * DD, nullptr, nullptr, t1, BL, 2 * DII, DD);
            conv_k<<<(BL * DII) / 256, 256, 0, stream>>>(
                t1, m_conv_w + (size_t)mi * DII * DCC, m_conv_b + mi * DII, t2);
            gemm_k<0, false, false><<<dim3(1, BL / GBM), 256, 0, stream>>>(
                t2, m_xproj + (size_t)mi * 2 * SS * DII, nullptr, nullptr, t5, BL, 2 * SS, DII);
            gemm_k<2, true, false><<<dim3(DII / GBN, BL / GBM), 256, 0, stream>>>(
                t2, m_dt_w + (size_t)mi * DII * DII, m_dt_b + mi * DII, nullptr, t3, BL, DII, DII);
            scan_k<<<BB, DII, 0, stream>>>(
                t3, t2, t5, t1, m_Alog + (size_t)mi * DII * SS, m_D + mi * DII, t4);
            gemm_k<0, false, true><<<dim3(DD / GBN, BL / GBM), 256, 0, stream>>>(
                t4, m_out_w + (size_t)mi * DD * DII, nullptr, x, x, BL, DD, DII);
            ++mi;
        }
    }

    // final layernorm
    ln_k<<<BL, 256, 0, stream>>>(x, f_g, f_b, xn);
    // lm logits -> out[0 : BL*V]
    gemm_k<0, false, false><<<dim3(VV / GBN, BL / GBM), 256, 0, stream>>>(
        xn, lm_w, nullptr, nullptr, out, BL, VV, DD);
    // readm / mort heads
    heads_k<<<8, 64, 0, stream>>>(xn, re_w, re_b, mo_w, mo_b, out);

    #undef GEMM
}

// Round 2
// 4771.859 us; speedup vs baseline: 2.6267x; 2.6267x over previous
//
#include <hip/hip_runtime.h>
#include <hip/hip_bf16.h>
#include <math.h>

// Problem constants
#define BB 4
#define LL 1024
#define BL (BB*LL)          // 4096 tokens
#define DD 256
#define VV 32000
#define HH 4
#define DH 64
#define SS 16
#define DCC 4
#define DII 512
#define NC 32               // scan chunks
#define CLN 32              // scan chunk length (NC*CLN == LL)

typedef float f32x4 __attribute__((ext_vector_type(4)));
typedef short bh8  __attribute__((ext_vector_type(8)));   // 8 bf16 (bit pattern)

__device__ __forceinline__ float sp_f(float x) {        // softplus
    return fmaxf(x, 0.f) + log1pf(expf(-fabsf(x)));
}
__device__ __forceinline__ float silu_f(float x) {
    return x / (1.f + expf(-x));
}
__device__ __forceinline__ short f2bf(float f) {
    __hip_bfloat16 h = __float2bfloat16(f);
    short s; __builtin_memcpy(&s, &h, 2); return s;
}

// ---------------------------------------------------------------- time feat
__global__ void feat_k(const float* __restrict__ ts, const float* __restrict__ freq,
                       const float* __restrict__ phase, float* __restrict__ feat) {
    int row = blockIdx.x, t = threadIdx.x;
    float tv = ts[row];
    int d = t & 127;
    float f = sp_f(freq[d]);
    float arg = tv * f + phase[d];
    feat[(size_t)row * DD + t] = (t < 128) ? sinf(arg) : cosf(arg);
}

// ---------------------------------------------------------------- embeddings
__global__ void embed_k(float* __restrict__ x, const int* __restrict__ ids,
                        const int* __restrict__ typ, const float* __restrict__ tok,
                        const float* __restrict__ tpe) {
    int row = blockIdx.x, t = threadIdx.x;
    x[(size_t)row * DD + t] += tok[(size_t)ids[row] * DD + t] + tpe[(size_t)typ[row] * DD + t];
}

// ---------------------------------------------------------------- layernorm (row of 256)
__global__ void ln_k(const float* __restrict__ x, const float* __restrict__ g,
                     const float* __restrict__ bbias, float* __restrict__ out) {
    __shared__ float red[8];
    int row = blockIdx.x, t = threadIdx.x;
    float v = x[(size_t)row * DD + t];
    float s = v;
    #pragma unroll
    for (int o = 32; o >= 1; o >>= 1) s += __shfl_xor(s, o);
    if ((t & 63) == 0) red[t >> 6] = s;
    __syncthreads();
    float mean = (red[0] + red[1] + red[2] + red[3]) * (1.f / 256.f);
    float d = v - mean;
    float s2 = d * d;
    #pragma unroll
    for (int o = 32; o >= 1; o >>= 1) s2 += __shfl_xor(s2, o);
    if ((t & 63) == 0) red[4 + (t >> 6)] = s2;
    __syncthreads();
    float var = (red[4] + red[5] + red[6] + red[7]) * (1.f / 256.f);
    out[(size_t)row * DD + t] = d * rsqrtf(var + 1e-5f) * g[t] + bbias[t];
}

// ---------------------------------------------------------------- MFMA GEMM: out = A(MxK) @ W(NxK)^T
// fp32 in (converted to bf16 during staging), fp32 out. 128x128 tile, BK=64,
// 4 waves (each a 64x64 quadrant), 16x16x32 bf16 MFMA, T2 XOR-swizzled LDS.
// Requires: M%128==0, N%128==0, K%64==0 (all shapes here satisfy this).
template <int ACT, bool HASB, bool HASR>
__global__ __launch_bounds__(256) void mgemm_k(
    const float* __restrict__ A, const float* __restrict__ W,
    const float* __restrict__ bias, const float* __restrict__ res,
    float* __restrict__ out, int M, int N, int K) {
    __shared__ __align__(16) char lds[32768];
    char* As = lds;
    char* Ws = lds + 16384;
    int tid = threadIdx.x;
    int bm = blockIdx.y * 128, bn = blockIdx.x * 128;
    int row = tid >> 1, half = tid & 1;       // staging: 128 rows x 2 halves
    int lane = tid & 63, wv = tid >> 6;
    int wm = wv >> 1, wn = wv & 1;            // wave quadrant
    int ro = lane & 15, kg = lane >> 4;       // fragment row / k-group

    f32x4 acc[4][4];
    #pragma unroll
    for (int i = 0; i < 4; ++i)
        #pragma unroll
        for (int j = 0; j < 4; ++j) acc[i][j] = (f32x4){0.f, 0.f, 0.f, 0.f};

    const float* ga = A + (size_t)(bm + row) * K + half * 32;
    const float* gw = W + (size_t)(bn + row) * K + half * 32;
    unsigned swb = (unsigned)(row * 128 + half * 64);
    unsigned sx  = (unsigned)((row & 7) << 4);

    for (int kk = 0; kk < K; kk += 64) {
        if (kk) __syncthreads();
        #pragma unroll
        for (int j = 0; j < 4; ++j) {
            float4 v0 = *(const float4*)(ga + j * 8);
            float4 v1 = *(const float4*)(ga + j * 8 + 4);
            bh8 p;
            p[0] = f2bf(v0.x); p[1] = f2bf(v0.y); p[2] = f2bf(v0.z); p[3] = f2bf(v0.w);
            p[4] = f2bf(v1.x); p[5] = f2bf(v1.y); p[6] = f2bf(v1.z); p[7] = f2bf(v1.w);
            *(bh8*)(As + ((swb + j * 16) ^ sx)) = p;
            float4 w0 = *(const float4*)(gw + j * 8);
            float4 w1 = *(const float4*)(gw + j * 8 + 4);
            bh8 q;
            q[0] = f2bf(w0.x); q[1] = f2bf(w0.y); q[2] = f2bf(w0.z); q[3] = f2bf(w0.w);
            q[4] = f2bf(w1.x); q[5] = f2bf(w1.y); q[6] = f2bf(w1.z); q[7] = f2bf(w1.w);
            *(bh8*)(Ws + ((swb + j * 16) ^ sx)) = q;
        }
        ga += 64; gw += 64;
        __syncthreads();
        #pragma unroll
        for (int ks = 0; ks < 2; ++ks) {
            bh8 af[4], bf_[4];
            #pragma unroll
            for (int m = 0; m < 4; ++m) {
                int r = wm * 64 + m * 16 + ro;
                af[m] = *(const bh8*)(As + (unsigned)((r * 128 + ks * 64 + kg * 16) ^ ((r & 7) << 4)));
            }
            #pragma unroll
            for (int n = 0; n < 4; ++n) {
                int r = wn * 64 + n * 16 + ro;
                bf_[n] = *(const bh8*)(Ws + (unsigned)((r * 128 + ks * 64 + kg * 16) ^ ((r & 7) << 4)));
            }
            #pragma unroll
            for (int m = 0; m < 4; ++m)
                #pragma unroll
                for (int n = 0; n < 4; ++n)
                    acc[m][n] = __builtin_amdgcn_mfma_f32_16x16x32_bf16(af[m], bf_[n], acc[m][n], 0, 0, 0);
        }
    }

    // epilogue: D row = (lane>>4)*4 + reg, col = lane&15  [guide §3, m89-verified]
    int cr = (lane >> 4) * 4, cc = lane & 15;
    #pragma unroll
    for (int mf = 0; mf < 4; ++mf) {
        #pragma unroll
        for (int nf = 0; nf < 4; ++nf) {
            int n = bn + wn * 64 + nf * 16 + cc;
            int mbase = bm + wm * 64 + mf * 16 + cr;
            float bv = HASB ? bias[n] : 0.f;
            f32x4 a = acc[mf][nf];
            #pragma unroll
            for (int r = 0; r < 4; ++r) {
                float v = a[r] + bv;
                if (ACT == 1) v = silu_f(v);
                if (ACT == 2) v = sp_f(v);
                if (HASR) v += res[(size_t)(mbase + r) * N + n];
                out[(size_t)(mbase + r) * N + n] = v;
            }
        }
    }
}

// ---------------------------------------------------------------- fp32 GEMM (kept for xproj, N=32)
constexpr int GBM = 64, GBN = 64, GBK = 16;
template <int ACT, bool HASB, bool HASR>
__global__ __launch_bounds__(256) void gemm_k(
    const float* __restrict__ A, const float* __restrict__ W,
    const float* __restrict__ bias, const float* __restrict__ res,
    float* __restrict__ out, int M, int N, int K) {
    __shared__ float As[GBK][GBM + 1];
    __shared__ float Ws[GBK][GBN + 1];
    int tid = threadIdx.x;
    int tx = tid & 15, ty = tid >> 4;
    int bm = blockIdx.y * GBM, bn = blockIdx.x * GBN;
    int lr = tid >> 2;
    int lk = (tid & 3) * 4;
    float acc[4][4] = {};
    for (int kk = 0; kk < K; kk += GBK) {
        int r = bm + lr;
        float4 av = make_float4(0.f, 0.f, 0.f, 0.f);
        if (r < M) av = *(const float4*)(A + (size_t)r * K + kk + lk);
        As[lk + 0][lr] = av.x; As[lk + 1][lr] = av.y;
        As[lk + 2][lr] = av.z; As[lk + 3][lr] = av.w;
        int n = bn + lr;
        float4 wvv = make_float4(0.f, 0.f, 0.f, 0.f);
        if (n < N) wvv = *(const float4*)(W + (size_t)n * K + kk + lk);
        Ws[lk + 0][lr] = wvv.x; Ws[lk + 1][lr] = wvv.y;
        Ws[lk + 2][lr] = wvv.z; Ws[lk + 3][lr] = wvv.w;
        __syncthreads();
        #pragma unroll
        for (int k = 0; k < GBK; ++k) {
            float a[4], bv[4];
            #pragma unroll
            for (int i = 0; i < 4; ++i) a[i] = As[k][ty * 4 + i];
            #pragma unroll
            for (int j = 0; j < 4; ++j) bv[j] = Ws[k][tx * 4 + j];
            #pragma unroll
            for (int i = 0; i < 4; ++i)
                #pragma unroll
                for (int j = 0; j < 4; ++j)
                    acc[i][j] = fmaf(a[i], bv[j], acc[i][j]);
        }
        __syncthreads();
    }
    #pragma unroll
    for (int i = 0; i < 4; ++i) {
        int m = bm + ty * 4 + i;
        if (m >= M) continue;
        #pragma unroll
        for (int j = 0; j < 4; ++j) {
            int n = bn + tx * 4 + j;
            if (n >= N) continue;
            float v = acc[i][j];
            if (HASB) v += bias[n];
            if (ACT == 1) v = silu_f(v);
            if (ACT == 2) v = sp_f(v);
            if (HASR) v += res[(size_t)m * N + n];
            out[(size_t)m * N + n] = v;
        }
    }
}

// ---------------------------------------------------------------- depthwise causal conv + silu
__global__ void conv_k(const float* __restrict__ xz, const float* __restrict__ w,
                       const float* __restrict__ cb, float* __restrict__ xb) {
    int idx = blockIdx.x * blockDim.x + threadIdx.x;  // BL*DI
    int c = idx & (DII - 1);
    int row = idx >> 9;
    int l = row & (LL - 1);
    int base = row - l;
    const float* wc = w + c * DCC;
    float s = cb[c];
    #pragma unroll
    for (int j = 0; j < DCC; ++j) {
        int ll = l - (DCC - 1) + j;
        if (ll >= 0) s = fmaf(wc[j], xz[((size_t)(base + ll)) * (2 * DII) + c], s);
    }
    xb[(size_t)idx] = silu_f(s);
}

// ---------------------------------------------------------------- chunked selective scan
// Diagonal recurrence h_l = a_l h_{l-1} + w_l per (b,di,s). 3 phases:
// A: per-chunk local scan from h=0, record (prod a, local h)    [256 blk x 256 thr]
// B: per-(b,di) serial combine over 32 chunks -> h_init[chunk]  [8 blk x 256 thr]
// C: per-chunk recompute from h_init, emit y                    [256 blk x 256 thr]
__global__ __launch_bounds__(256) void scanA_k(
    const float* __restrict__ dt, const float* __restrict__ xb,
    const float* __restrict__ bc, const float* __restrict__ Alog,
    float* __restrict__ P, float* __restrict__ Lc) {
    int bid = blockIdx.x;
    int b = bid >> 6;
    int c = (bid >> 1) & 31;
    int di = (bid & 1) * 256 + threadIdx.x;
    float A[SS], ap[SS], h[SS];
    #pragma unroll
    for (int s = 0; s < SS; ++s) { A[s] = -expf(Alog[di * SS + s]); ap[s] = 1.f; h[s] = 0.f; }
    for (int l = c * CLN; l < c * CLN + CLN; ++l) {
        size_t base = (size_t)b * LL + l;
        float dtv = dt[base * DII + di];
        float xv  = xb[base * DII + di];
        const float* Bt = bc + base * (2 * SS);
        float u = dtv * xv;
        #pragma unroll
        for (int s = 0; s < SS; ++s) {
            float a = expf(dtv * A[s]);
            ap[s] *= a;
            h[s] = fmaf(a, h[s], u * Bt[s]);
        }
    }
    size_t o = (((size_t)c * BB + b) * DII + di) * SS;
    #pragma unroll
    for (int j = 0; j < 4; ++j) {
        *(f32x4*)(P  + o + j * 4) = (f32x4){ap[j*4], ap[j*4+1], ap[j*4+2], ap[j*4+3]};
        *(f32x4*)(Lc + o + j * 4) = (f32x4){h[j*4],  h[j*4+1],  h[j*4+2],  h[j*4+3]};
    }
}

__global__ __launch_bounds__(256) void scanB_k(const float* __restrict__ P, float* __restrict__ Lc) {
    int t = blockIdx.x * 256 + threadIdx.x;   // 0..2047
    int b = t >> 9, di = t & (DII - 1);
    f32x4 h[4];
    #pragma unroll
    for (int j = 0; j < 4; ++j) h[j] = (f32x4){0.f, 0.f, 0.f, 0.f};
    for (int c = 0; c < NC; ++c) {
        size_t o = (((size_t)c * BB + b) * DII + di) * SS;
        #pragma unroll
        for (int j = 0; j < 4; ++j) {
            f32x4 p  = *(const f32x4*)(P  + o + j * 4);
            f32x4 lc = *(const f32x4*)(Lc + o + j * 4);
            *(f32x4*)(Lc + o + j * 4) = h[j];     // h_init for chunk c (in-place)
            h[j] = p * h[j] + lc;
        }
    }
}

__global__ __launch_bounds__(256) void scanC_k(
    const float* __restrict__ dt, const float* __restrict__ xb,
    const float* __restrict__ bc, const float* __restrict__ xz,
    const float* __restrict__ Alog, const float* __restrict__ Dp,
    const float* __restrict__ Hi, float* __restrict__ y) {
    int bid = blockIdx.x;
    int b = bid >> 6;
    int c = (bid >> 1) & 31;
    int di = (bid & 1) * 256 + threadIdx.x;
    float A[SS], h[SS];
    #pragma unroll
    for (int s = 0; s < SS; ++s) A[s] = -expf(Alog[di * SS + s]);
    size_t o = (((size_t)c * BB + b) * DII + di) * SS;
    #pragma unroll
    for (int s = 0; s < SS; ++s) h[s] = Hi[o + s];
    float Dv = Dp[di];
    for (int l = c * CLN; l < c * CLN + CLN; ++l) {
        size_t base = (size_t)b * LL + l;
        float dtv = dt[base * DII + di];
        float xv  = xb[base * DII + di];
        float zv  = xz[base * (2 * DII) + DII + di];
        const float* Bt = bc + base * (2 * SS);
        float u = dtv * xv;
        float acc = 0.f;
        #pragma unroll
        for (int s = 0; s < SS; ++s) {
            float a = expf(dtv * A[s]);
            h[s] = fmaf(a, h[s], u * Bt[s]);
            acc = fmaf(h[s], Bt[SS + s], acc);
        }
        y[base * DII + di] = fmaf(Dv, xv, acc) * silu_f(zv);
    }
}

// ---------------------------------------------------------------- attention: one wave per (b,h,q), online softmax
__global__ __launch_bounds__(64) void attn_k(
    const float* __restrict__ qkv, const float* __restrict__ ts,
    const int* __restrict__ mask, const float* __restrict__ decay,
    float* __restrict__ out) {
    int lane = threadIdx.x;
    int q = blockIdx.x & (LL - 1);
    int h = (blockIdx.x >> 10) & (HH - 1);
    int b = blockIdx.x >> 12;
    const float* qrow = qkv + ((size_t)(b * LL + q)) * (3 * DD) + h * DH;
    float qd = qrow[lane];
    float tq = ts[b * LL + q];
    float sp = sp_f(decay[h]);
    float m = -INFINITY, den = 0.f, acc = 0.f;
    for (int k = 0; k <= q; ++k) {
        if (mask[b * LL + k] == 0) continue;
        const float* kr = qkv + ((size_t)(b * LL + k)) * (3 * DD) + DD + h * DH;
        float p = qd * kr[lane];
        #pragma unroll
        for (int o = 32; o >= 1; o >>= 1) p += __shfl_xor(p, o);
        float s = p * 0.125f - sp * fabsf(tq - ts[b * LL + k]) * (1.f / 24.f);
        float mn = fmaxf(m, s);
        float sc = expf(m - mn);
        float w = expf(s - mn);
        den = den * sc + w;
        const float* vr = qkv + ((size_t)(b * LL + k)) * (3 * DD) + 2 * DD + h * DH;
        acc = acc * sc + w * vr[lane];
        m = mn;
    }
    out[((size_t)(b * LL + q)) * DD + h * DH + lane] = acc / den;
}

// ---------------------------------------------------------------- readm / mort heads
__global__ __launch_bounds__(64) void heads_k(
    const float* __restrict__ xn, const float* __restrict__ re_w, const float* __restrict__ re_b,
    const float* __restrict__ mo_w, const float* __restrict__ mo_b, float* __restrict__ out) {
    int lane = threadIdx.x;
    int b = blockIdx.x & 3;
    int which = blockIdx.x >> 2;
    const float* wv = which ? mo_w : re_w;
    const float* row = xn + (size_t)b * LL * DD;
    float s = 0.f;
    #pragma unroll
    for (int d = 0; d < DD / 64; ++d) s = fmaf(row[lane + d * 64], wv[lane + d * 64], s);
    #pragma unroll
    for (int o = 32; o >= 1; o >>= 1) s += __shfl_xor(s, o);
    if (lane == 0) out[(size_t)VV * BL + which * 4 + b] = s + (which ? mo_b[0] : re_b[0]);
}

// ================================================================ host
extern "C" void kernel_launch(void* const* d_in, const int* in_sizes, int n_in,
                              void* d_out, int out_size, void* d_ws, size_t ws_size,
                              hipStream_t stream) {
    const int*   ids      = (const int*)  d_in[0];
    const int*   typ      = (const int*)  d_in[1];
    const float* ts       = (const float*)d_in[2];
    const int*   amask    = (const int*)  d_in[3];
    const float* tok_emb  = (const float*)d_in[4];
    const float* type_emb = (const float*)d_in[5];
    const float* te_freq  = (const float*)d_in[6];
    const float* te_phase = (const float*)d_in[7];
    const float* te_w     = (const float*)d_in[8];
    const float* te_b     = (const float*)d_in[9];
    const float* m_norm_g = (const float*)d_in[10];
    const float* m_norm_b = (const float*)d_in[11];
    const float* m_in_w   = (const float*)d_in[12];
    const float* m_conv_w = (const float*)d_in[13];
    const float* m_conv_b = (const float*)d_in[14];
    const float* m_xproj  = (const float*)d_in[15];
    const float* m_dt_w   = (const float*)d_in[16];
    const float* m_dt_b   = (const float*)d_in[17];
    const float* m_Alog   = (const float*)d_in[18];
    const float* m_D      = (const float*)d_in[19];
    const float* m_out_w  = (const float*)d_in[20];
    const float* a_norm_g = (const float*)d_in[21];
    const float* a_norm_b = (const float*)d_in[22];
    const float* a_qkv_w  = (const float*)d_in[23];
    const float* a_out_w  = (const float*)d_in[24];
    const float* a_decay  = (const float*)d_in[25];
    const float* a_ffg    = (const float*)d_in[26];
    const float* a_ffb    = (const float*)d_in[27];
    const float* a_ff1    = (const float*)d_in[28];
    const float* a_ff2    = (const float*)d_in[29];
    const float* f_g      = (const float*)d_in[30];
    const float* f_b      = (const float*)d_in[31];
    const float* lm_w     = (const float*)d_in[32];
    const float* re_w     = (const float*)d_in[33];
    const float* re_b     = (const float*)d_in[34];
    const float* mo_w     = (const float*)d_in[35];
    const float* mo_b     = (const float*)d_in[36];

    float* out = (float*)d_out;
    float* ws  = (float*)d_ws;

    // workspace layout (floats): total 14.125M floats = 56.5 MB
    float* x   = ws;                          // BL*D
    float* xn  = x  + (size_t)BL * DD;        // BL*D
    float* t1  = xn + (size_t)BL * DD;        // BL*1024 (xz / qkv / ffh)
    float* t2  = t1 + (size_t)BL * 1024;      // BL*512  (xb conv out / attn out)
    float* t3  = t2 + (size_t)BL * DII;       // BL*512  (dt)
    float* t4  = t3 + (size_t)BL * DII;       // BL*512  (scan y)
    float* t5  = t4 + (size_t)BL * DII;       // BL*32   (B,C)
    float* sP  = t5 + (size_t)BL * 2 * SS;    // NC*B*DI*S = 1M (chunk a-products)
    float* sL  = sP + (size_t)NC * BB * DII * SS; // 1M (chunk locals -> h_init)

    // 1. time features -> xn (scratch)
    feat_k<<<BL, 256, 0, stream>>>(ts, te_freq, te_phase, xn);
    // 2. enc = feat @ te_w^T + te_b -> x   (MFMA)
    mgemm_k<0, true, false><<<dim3(DD / 128, BL / 128), 256, 0, stream>>>(
        xn, te_w, te_b, nullptr, x, BL, DD, DD);
    // 3. x += tok_emb[ids] + type_emb[typ]
    embed_k<<<BL, 256, 0, stream>>>(x, ids, typ, tok_emb, type_emb);

    int mi = 0, ai = 0;
    for (int i = 0; i < 8; ++i) {
        if ((i + 1) % 4 == 0) {
            // ------------- attention block ai
            ln_k<<<BL, 256, 0, stream>>>(x, a_norm_g + ai * DD, a_norm_b + ai * DD, xn);
            mgemm_k<0, false, false><<<dim3((3 * DD) / 128, BL / 128), 256, 0, stream>>>(
                xn, a_qkv_w + (size_t)ai * 3 * DD * DD, nullptr, nullptr, t1, BL, 3 * DD, DD);
            attn_k<<<BB * HH * LL, 64, 0, stream>>>(t1, ts, amask, a_decay + ai * HH, t2);
            mgemm_k<0, false, true><<<dim3(DD / 128, BL / 128), 256, 0, stream>>>(
                t2, a_out_w + (size_t)ai * DD * DD, nullptr, x, x, BL, DD, DD);
            ln_k<<<BL, 256, 0, stream>>>(x, a_ffg + ai * DD, a_ffb + ai * DD, xn);
            mgemm_k<1, false, false><<<dim3((4 * DD) / 128, BL / 128), 256, 0, stream>>>(
                xn, a_ff1 + (size_t)ai * 4 * DD * DD, nullptr, nullptr, t1, BL, 4 * DD, DD);
            mgemm_k<0, false, true><<<dim3(DD / 128, BL / 128), 256, 0, stream>>>(
                t1, a_ff2 + (size_t)ai * DD * 4 * DD, nullptr, x, x, BL, DD, 4 * DD);
            ++ai;
        } else {
            // ------------- mamba block mi
            ln_k<<<BL, 256, 0, stream>>>(x, m_norm_g + mi * DD, m_norm_b + mi * DD, xn);
            mgemm_k<0, false, false><<<dim3((2 * DII) / 128, BL / 128), 256, 0, stream>>>(
                xn, m_in_w + (size_t)mi * 2 * DII * DD, nullptr, nullptr, t1, BL, 2 * DII, DD);
            conv_k<<<(BL * DII) / 256, 256, 0, stream>>>(
                t1, m_conv_w + (size_t)mi * DII * DCC, m_conv_b + mi * DII, t2);
            gemm_k<0, false, false><<<dim3(1, BL / GBM), 256, 0, stream>>>(
                t2, m_xproj + (size_t)mi * 2 * SS * DII, nullptr, nullptr, t5, BL, 2 * SS, DII);
            mgemm_k<2, true, false><<<dim3(DII / 128, BL / 128), 256, 0, stream>>>(
                t2, m_dt_w + (size_t)mi * DII * DII, m_dt_b + mi * DII, nullptr, t3, BL, DII, DII);
            scanA_k<<<256, 256, 0, stream>>>(
                t3, t2, t5, m_Alog + (size_t)mi * DII * SS, sP, sL);
            scanB_k<<<8, 256, 0, stream>>>(sP, sL);
            scanC_k<<<256, 256, 0, stream>>>(
                t3, t2, t5, t1, m_Alog + (size_t)mi * DII * SS, m_D + mi * DII, sL, t4);
            mgemm_k<0, false, true><<<dim3(DD / 128, BL / 128), 256, 0, stream>>>(
                t4, m_out_w + (size_t)mi * DD * DII, nullptr, x, x, BL, DD, DII);
            ++mi;
        }
    }

    // final layernorm
    ln_k<<<BL, 256, 0, stream>>>(x, f_g, f_b, xn);
    // lm logits -> out[0 : BL*V]   (MFMA)
    mgemm_k<0, false, false><<<dim3(VV / 128, BL / 128), 256, 0, stream>>>(
        xn, lm_w, nullptr, nullptr, out, BL, VV, DD);
    // readm / mort heads
    heads_k<<<8, 64, 0, stream>>>(xn, re_w, re_b, mo_w, mo_b, out);
}

// Round 3
// 2689.059 us; speedup vs baseline: 4.6611x; 1.7745x over previous
//
#include <hip/hip_runtime.h>
#include <hip/hip_bf16.h>
#include <math.h>

// Problem constants
#define BB 4
#define LL 1024
#define BL (BB*LL)          // 4096 tokens
#define DD 256
#define VV 32000
#define HH 4
#define DH 64
#define SS 16
#define DCC 4
#define DII 512
#define NC 32               // scan chunks
#define CLN 32              // scan chunk length (NC*CLN == LL)

typedef float f32x4 __attribute__((ext_vector_type(4)));
typedef short bh8  __attribute__((ext_vector_type(8)));   // 8 bf16 (bit pattern)

__device__ __forceinline__ float sp_f(float x) {        // softplus
    return fmaxf(x, 0.f) + log1pf(expf(-fabsf(x)));
}
__device__ __forceinline__ float silu_f(float x) {
    return x / (1.f + expf(-x));
}
__device__ __forceinline__ short f2bf(float f) {
    __hip_bfloat16 h = __float2bfloat16(f);
    short s; __builtin_memcpy(&s, &h, 2); return s;
}
__device__ __forceinline__ bh8 pack8(float4 a, float4 b) {
    bh8 p;
    p[0] = f2bf(a.x); p[1] = f2bf(a.y); p[2] = f2bf(a.z); p[3] = f2bf(a.w);
    p[4] = f2bf(b.x); p[5] = f2bf(b.y); p[6] = f2bf(b.z); p[7] = f2bf(b.w);
    return p;
}

// ---------------------------------------------------------------- time feat
__global__ void feat_k(const float* __restrict__ ts, const float* __restrict__ freq,
                       const float* __restrict__ phase, float* __restrict__ feat) {
    int row = blockIdx.x, t = threadIdx.x;
    float tv = ts[row];
    int d = t & 127;
    float f = sp_f(freq[d]);
    float arg = tv * f + phase[d];
    feat[(size_t)row * DD + t] = (t < 128) ? sinf(arg) : cosf(arg);
}

// ---------------------------------------------------------------- embeddings
__global__ void embed_k(float* __restrict__ x, const int* __restrict__ ids,
                        const int* __restrict__ typ, const float* __restrict__ tok,
                        const float* __restrict__ tpe) {
    int row = blockIdx.x, t = threadIdx.x;
    x[(size_t)row * DD + t] += tok[(size_t)ids[row] * DD + t] + tpe[(size_t)typ[row] * DD + t];
}

// ---------------------------------------------------------------- layernorm (row of 256)
__global__ void ln_k(const float* __restrict__ x, const float* __restrict__ g,
                     const float* __restrict__ bbias, float* __restrict__ out) {
    __shared__ float red[8];
    int row = blockIdx.x, t = threadIdx.x;
    float v = x[(size_t)row * DD + t];
    float s = v;
    #pragma unroll
    for (int o = 32; o >= 1; o >>= 1) s += __shfl_xor(s, o);
    if ((t & 63) == 0) red[t >> 6] = s;
    __syncthreads();
    float mean = (red[0] + red[1] + red[2] + red[3]) * (1.f / 256.f);
    float d = v - mean;
    float s2 = d * d;
    #pragma unroll
    for (int o = 32; o >= 1; o >>= 1) s2 += __shfl_xor(s2, o);
    if ((t & 63) == 0) red[4 + (t >> 6)] = s2;
    __syncthreads();
    float var = (red[4] + red[5] + red[6] + red[7]) * (1.f / 256.f);
    out[(size_t)row * DD + t] = d * rsqrtf(var + 1e-5f) * g[t] + bbias[t];
}

// ---------------------------------------------------------------- MFMA GEMM: out = A(MxK) @ W(NxK)^T
template <int ACT, bool HASB, bool HASR>
__global__ __launch_bounds__(256) void mgemm_k(
    const float* __restrict__ A, const float* __restrict__ W,
    const float* __restrict__ bias, const float* __restrict__ res,
    float* __restrict__ out, int M, int N, int K) {
    __shared__ __align__(16) char lds[32768];
    char* As = lds;
    char* Ws = lds + 16384;
    int tid = threadIdx.x;
    int bm = blockIdx.y * 128, bn = blockIdx.x * 128;
    int row = tid >> 1, half = tid & 1;       // staging: 128 rows x 2 halves
    int lane = tid & 63, wv = tid >> 6;
    int wm = wv >> 1, wn = wv & 1;            // wave quadrant
    int ro = lane & 15, kg = lane >> 4;       // fragment row / k-group

    f32x4 acc[4][4];
    #pragma unroll
    for (int i = 0; i < 4; ++i)
        #pragma unroll
        for (int j = 0; j < 4; ++j) acc[i][j] = (f32x4){0.f, 0.f, 0.f, 0.f};

    const float* ga = A + (size_t)(bm + row) * K + half * 32;
    const float* gw = W + (size_t)(bn + row) * K + half * 32;
    unsigned swb = (unsigned)(row * 128 + half * 64);
    unsigned sx  = (unsigned)((row & 7) << 4);

    for (int kk = 0; kk < K; kk += 64) {
        if (kk) __syncthreads();
        #pragma unroll
        for (int j = 0; j < 4; ++j) {
            float4 v0 = *(const float4*)(ga + j * 8);
            float4 v1 = *(const float4*)(ga + j * 8 + 4);
            *(bh8*)(As + ((swb + j * 16) ^ sx)) = pack8(v0, v1);
            float4 w0 = *(const float4*)(gw + j * 8);
            float4 w1 = *(const float4*)(gw + j * 8 + 4);
            *(bh8*)(Ws + ((swb + j * 16) ^ sx)) = pack8(w0, w1);
        }
        ga += 64; gw += 64;
        __syncthreads();
        #pragma unroll
        for (int ks = 0; ks < 2; ++ks) {
            bh8 af[4], bf_[4];
            #pragma unroll
            for (int m = 0; m < 4; ++m) {
                int r = wm * 64 + m * 16 + ro;
                af[m] = *(const bh8*)(As + (unsigned)((r * 128 + ks * 64 + kg * 16) ^ ((r & 7) << 4)));
            }
            #pragma unroll
            for (int n = 0; n < 4; ++n) {
                int r = wn * 64 + n * 16 + ro;
                bf_[n] = *(const bh8*)(Ws + (unsigned)((r * 128 + ks * 64 + kg * 16) ^ ((r & 7) << 4)));
            }
            #pragma unroll
            for (int m = 0; m < 4; ++m)
                #pragma unroll
                for (int n = 0; n < 4; ++n)
                    acc[m][n] = __builtin_amdgcn_mfma_f32_16x16x32_bf16(af[m], bf_[n], acc[m][n], 0, 0, 0);
        }
    }

    // epilogue: D row = (lane>>4)*4 + reg, col = lane&15
    int cr = (lane >> 4) * 4, cc = lane & 15;
    #pragma unroll
    for (int mf = 0; mf < 4; ++mf) {
        #pragma unroll
        for (int nf = 0; nf < 4; ++nf) {
            int n = bn + wn * 64 + nf * 16 + cc;
            int mbase = bm + wm * 64 + mf * 16 + cr;
            float bv = HASB ? bias[n] : 0.f;
            f32x4 a = acc[mf][nf];
            #pragma unroll
            for (int r = 0; r < 4; ++r) {
                float v = a[r] + bv;
                if (ACT == 1) v = silu_f(v);
                if (ACT == 2) v = sp_f(v);
                if (HASR) v += res[(size_t)(mbase + r) * N + n];
                out[(size_t)(mbase + r) * N + n] = v;
            }
        }
    }
}

// ---------------------------------------------------------------- fp32 GEMM (kept for xproj, N=32)
constexpr int GBM = 64, GBN = 64, GBK = 16;
template <int ACT, bool HASB, bool HASR>
__global__ __launch_bounds__(256) void gemm_k(
    const float* __restrict__ A, const float* __restrict__ W,
    const float* __restrict__ bias, const float* __restrict__ res,
    float* __restrict__ out, int M, int N, int K) {
    __shared__ float As[GBK][GBM + 1];
    __shared__ float Ws[GBK][GBN + 1];
    int tid = threadIdx.x;
    int tx = tid & 15, ty = tid >> 4;
    int bm = blockIdx.y * GBM, bn = blockIdx.x * GBN;
    int lr = tid >> 2;
    int lk = (tid & 3) * 4;
    float acc[4][4] = {};
    for (int kk = 0; kk < K; kk += GBK) {
        int r = bm + lr;
        float4 av = make_float4(0.f, 0.f, 0.f, 0.f);
        if (r < M) av = *(const float4*)(A + (size_t)r * K + kk + lk);
        As[lk + 0][lr] = av.x; As[lk + 1][lr] = av.y;
        As[lk + 2][lr] = av.z; As[lk + 3][lr] = av.w;
        int n = bn + lr;
        float4 wvv = make_float4(0.f, 0.f, 0.f, 0.f);
        if (n < N) wvv = *(const float4*)(W + (size_t)n * K + kk + lk);
        Ws[lk + 0][lr] = wvv.x; Ws[lk + 1][lr] = wvv.y;
        Ws[lk + 2][lr] = wvv.z; Ws[lk + 3][lr] = wvv.w;
        __syncthreads();
        #pragma unroll
        for (int k = 0; k < GBK; ++k) {
            float a[4], bv[4];
            #pragma unroll
            for (int i = 0; i < 4; ++i) a[i] = As[k][ty * 4 + i];
            #pragma unroll
            for (int j = 0; j < 4; ++j) bv[j] = Ws[k][tx * 4 + j];
            #pragma unroll
            for (int i = 0; i < 4; ++i)
                #pragma unroll
                for (int j = 0; j < 4; ++j)
                    acc[i][j] = fmaf(a[i], bv[j], acc[i][j]);
        }
        __syncthreads();
    }
    #pragma unroll
    for (int i = 0; i < 4; ++i) {
        int m = bm + ty * 4 + i;
        if (m >= M) continue;
        #pragma unroll
        for (int j = 0; j < 4; ++j) {
            int n = bn + tx * 4 + j;
            if (n >= N) continue;
            float v = acc[i][j];
            if (HASB) v += bias[n];
            if (ACT == 1) v = silu_f(v);
            if (ACT == 2) v = sp_f(v);
            if (HASR) v += res[(size_t)m * N + n];
            out[(size_t)m * N + n] = v;
        }
    }
}

// ---------------------------------------------------------------- depthwise causal conv + silu
__global__ void conv_k(const float* __restrict__ xz, const float* __restrict__ w,
                       const float* __restrict__ cb, float* __restrict__ xb) {
    int idx = blockIdx.x * blockDim.x + threadIdx.x;  // BL*DI
    int c = idx & (DII - 1);
    int row = idx >> 9;
    int l = row & (LL - 1);
    int base = row - l;
    const float* wc = w + c * DCC;
    float s = cb[c];
    #pragma unroll
    for (int j = 0; j < DCC; ++j) {
        int ll = l - (DCC - 1) + j;
        if (ll >= 0) s = fmaf(wc[j], xz[((size_t)(base + ll)) * (2 * DII) + c], s);
    }
    xb[(size_t)idx] = silu_f(s);
}

// ---------------------------------------------------------------- chunked selective scan (A/B/C phases)
__global__ __launch_bounds__(256) void scanA_k(
    const float* __restrict__ dt, const float* __restrict__ xb,
    const float* __restrict__ bc, const float* __restrict__ Alog,
    float* __restrict__ P, float* __restrict__ Lc) {
    int bid = blockIdx.x;
    int b = bid >> 6;
    int c = (bid >> 1) & 31;
    int di = (bid & 1) * 256 + threadIdx.x;
    float A[SS], ap[SS], h[SS];
    #pragma unroll
    for (int s = 0; s < SS; ++s) { A[s] = -expf(Alog[di * SS + s]); ap[s] = 1.f; h[s] = 0.f; }
    for (int l = c * CLN; l < c * CLN + CLN; ++l) {
        size_t base = (size_t)b * LL + l;
        float dtv = dt[base * DII + di];
        float xv  = xb[base * DII + di];
        const float* Bt = bc + base * (2 * SS);
        float u = dtv * xv;
        #pragma unroll
        for (int s = 0; s < SS; ++s) {
            float a = expf(dtv * A[s]);
            ap[s] *= a;
            h[s] = fmaf(a, h[s], u * Bt[s]);
        }
    }
    size_t o = (((size_t)c * BB + b) * DII + di) * SS;
    #pragma unroll
    for (int j = 0; j < 4; ++j) {
        *(f32x4*)(P  + o + j * 4) = (f32x4){ap[j*4], ap[j*4+1], ap[j*4+2], ap[j*4+3]};
        *(f32x4*)(Lc + o + j * 4) = (f32x4){h[j*4],  h[j*4+1],  h[j*4+2],  h[j*4+3]};
    }
}

__global__ __launch_bounds__(256) void scanB_k(const float* __restrict__ P, float* __restrict__ Lc) {
    int t = blockIdx.x * 256 + threadIdx.x;   // 0..2047
    int b = t >> 9, di = t & (DII - 1);
    f32x4 h[4];
    #pragma unroll
    for (int j = 0; j < 4; ++j) h[j] = (f32x4){0.f, 0.f, 0.f, 0.f};
    for (int c = 0; c < NC; ++c) {
        size_t o = (((size_t)c * BB + b) * DII + di) * SS;
        #pragma unroll
        for (int j = 0; j < 4; ++j) {
            f32x4 p  = *(const f32x4*)(P  + o + j * 4);
            f32x4 lc = *(const f32x4*)(Lc + o + j * 4);
            *(f32x4*)(Lc + o + j * 4) = h[j];     // h_init for chunk c (in-place)
            h[j] = p * h[j] + lc;
        }
    }
}

__global__ __launch_bounds__(256) void scanC_k(
    const float* __restrict__ dt, const float* __restrict__ xb,
    const float* __restrict__ bc, const float* __restrict__ xz,
    const float* __restrict__ Alog, const float* __restrict__ Dp,
    const float* __restrict__ Hi, float* __restrict__ y) {
    int bid = blockIdx.x;
    int b = bid >> 6;
    int c = (bid >> 1) & 31;
    int di = (bid & 1) * 256 + threadIdx.x;
    float A[SS], h[SS];
    #pragma unroll
    for (int s = 0; s < SS; ++s) A[s] = -expf(Alog[di * SS + s]);
    size_t o = (((size_t)c * BB + b) * DII + di) * SS;
    #pragma unroll
    for (int s = 0; s < SS; ++s) h[s] = Hi[o + s];
    float Dv = Dp[di];
    for (int l = c * CLN; l < c * CLN + CLN; ++l) {
        size_t base = (size_t)b * LL + l;
        float dtv = dt[base * DII + di];
        float xv  = xb[base * DII + di];
        float zv  = xz[base * (2 * DII) + DII + di];
        const float* Bt = bc + base * (2 * SS);
        float u = dtv * xv;
        float acc = 0.f;
        #pragma unroll
        for (int s = 0; s < SS; ++s) {
            float a = expf(dtv * A[s]);
            h[s] = fmaf(a, h[s], u * Bt[s]);
            acc = fmaf(h[s], Bt[SS + s], acc);
        }
        y[base * DII + di] = fmaf(Dv, xv, acc) * silu_f(zv);
    }
}

// ---------------------------------------------------------------- flash attention (MFMA)
// Block = 4 waves = one (b, h, 64-row q-tile). Each wave owns 16 q-rows.
// Per 64-key tile: stage K bf16 [64][64] (XOR-swizzled) + V^T bf16 [dh][k] in LDS,
// QK^T via 8 MFMA, fp32 softmax (decay/causal/mask), online rescale,
// P->bf16 via wave-private LDS, PV via 8 MFMA against V^T B-fragments.
__global__ __launch_bounds__(256) void fattn_k(
    const float* __restrict__ qkv, const float* __restrict__ ts,
    const int* __restrict__ mask, const float* __restrict__ decay,
    float* __restrict__ out) {
    __shared__ __align__(16) char ksm[8192];
    __shared__ __align__(16) char vsm[8192];
    __shared__ __align__(16) char psm[8192];
    __shared__ float tsk[64];
    __shared__ int   msk[64];

    int tid = threadIdx.x;
    int lane = tid & 63, wvi = tid >> 6;
    int qt = blockIdx.x & 15;
    int h  = (blockIdx.x >> 4) & 3;
    int b  = blockIdx.x >> 6;
    int q0 = qt * 64;
    int g = lane >> 4, c = lane & 15;

    // Q A-fragments: row = q0 + wvi*16 + c, k(dh) = ks*32 + g*8 + i
    bh8 qf[2];
    {
        const float* qrow = qkv + ((size_t)(b * LL + q0 + wvi * 16 + c)) * (3 * DD) + h * DH;
        #pragma unroll
        for (int ks = 0; ks < 2; ++ks) {
            float4 a  = *(const float4*)(qrow + ks * 32 + g * 8);
            float4 bb = *(const float4*)(qrow + ks * 32 + g * 8 + 4);
            qf[ks] = pack8(a, bb);
        }
    }
    float tq[4];
    #pragma unroll
    for (int j = 0; j < 4; ++j) tq[j] = ts[b * LL + q0 + wvi * 16 + g * 4 + j];
    float spd = sp_f(decay[h]);

    f32x4 o[4];
    #pragma unroll
    for (int n = 0; n < 4; ++n) o[n] = (f32x4){0.f, 0.f, 0.f, 0.f};
    float mrow[4] = {-INFINITY, -INFINITY, -INFINITY, -INFINITY};
    float drow[4] = {0.f, 0.f, 0.f, 0.f};

    char* pw = psm + wvi * 2048;   // wave-private P buffer (16x64 bf16)

    for (int kt = 0; kt <= qt; ++kt) {
        int k0 = kt * 64;
        __syncthreads();
        // ---- stage K (row-major, swizzled) and V^T (transposed scalar writes)
        {
            int row = tid >> 2, qq = tid & 3;
            const float* kr = qkv + ((size_t)(b * LL + k0 + row)) * (3 * DD) + DD + h * DH + qq * 16;
            float4 k0v = *(const float4*)(kr);
            float4 k1v = *(const float4*)(kr + 4);
            float4 k2v = *(const float4*)(kr + 8);
            float4 k3v = *(const float4*)(kr + 12);
            unsigned sw = (unsigned)((row & 7) << 4);
            unsigned base = (unsigned)(row * 128 + qq * 32);
            *(bh8*)(ksm + (base ^ sw)) = pack8(k0v, k1v);
            *(bh8*)(ksm + ((base + 16) ^ sw)) = pack8(k2v, k3v);
            const float* vr = qkv + ((size_t)(b * LL + k0 + row)) * (3 * DD) + 2 * DD + h * DH + qq * 16;
            #pragma unroll
            for (int i = 0; i < 16; ++i) {
                int dh = qq * 16 + i;
                *(short*)(vsm + (unsigned)((dh * 128 + row * 2) ^ ((dh & 7) << 4))) = f2bf(vr[i]);
            }
            if (tid < 64) { tsk[tid] = ts[b * LL + k0 + tid]; msk[tid] = mask[b * LL + k0 + tid]; }
        }
        __syncthreads();

        // ---- S = Q K^T   (wave strip: 16 q-rows x 64 k-cols)
        f32x4 sf[4];
        #pragma unroll
        for (int n = 0; n < 4; ++n) sf[n] = (f32x4){0.f, 0.f, 0.f, 0.f};
        #pragma unroll
        for (int ks = 0; ks < 2; ++ks) {
            #pragma unroll
            for (int nf = 0; nf < 4; ++nf) {
                int rr = nf * 16 + c;
                bh8 kf = *(const bh8*)(ksm + (unsigned)((rr * 128 + ks * 64 + g * 16) ^ ((rr & 7) << 4)));
                sf[nf] = __builtin_amdgcn_mfma_f32_16x16x32_bf16(qf[ks], kf, sf[nf], 0, 0, 0);
            }
        }
        // ---- decay + causal + mask, track row max
        float mnew[4] = {mrow[0], mrow[1], mrow[2], mrow[3]};
        #pragma unroll
        for (int nf = 0; nf < 4; ++nf) {
            int kk = c + 16 * nf;
            float tk = tsk[kk];
            bool md = (msk[kk] == 0);
            #pragma unroll
            for (int j = 0; j < 4; ++j) {
                int qrow = q0 + wvi * 16 + g * 4 + j;
                float s = sf[nf][j] * 0.125f - spd * fabsf(tq[j] - tk) * (1.f / 24.f);
                bool dead = md || (k0 + kk > qrow);
                s = dead ? -INFINITY : s;
                sf[nf][j] = s;
                mnew[j] = fmaxf(mnew[j], s);
            }
        }
        #pragma unroll
        for (int off = 1; off <= 8; off <<= 1)
            #pragma unroll
            for (int j = 0; j < 4; ++j) mnew[j] = fmaxf(mnew[j], __shfl_xor(mnew[j], off));
        float scl[4], psum[4];
        #pragma unroll
        for (int j = 0; j < 4; ++j) {
            scl[j] = (mnew[j] == -INFINITY) ? 1.f : expf(mrow[j] - mnew[j]);
            psum[j] = 0.f;
            mrow[j] = mnew[j];
        }
        // ---- P = exp(s - m) -> bf16 into wave-private LDS
        #pragma unroll
        for (int nf = 0; nf < 4; ++nf) {
            #pragma unroll
            for (int j = 0; j < 4; ++j) {
                float s = sf[nf][j];
                float p = (s == -INFINITY) ? 0.f : expf(s - mrow[j]);
                psum[j] += p;
                int row = g * 4 + j;
                *(short*)(pw + (unsigned)((row * 128 + (c + 16 * nf) * 2) ^ ((row & 7) << 4))) = f2bf(p);
            }
        }
        #pragma unroll
        for (int off = 1; off <= 8; off <<= 1)
            #pragma unroll
            for (int j = 0; j < 4; ++j) psum[j] += __shfl_xor(psum[j], off);
        #pragma unroll
        for (int j = 0; j < 4; ++j) drow[j] = drow[j] * scl[j] + psum[j];
        #pragma unroll
        for (int n = 0; n < 4; ++n)
            #pragma unroll
            for (int j = 0; j < 4; ++j) o[n][j] *= scl[j];
        // ---- O += P V  (A = P rows, B = V^T rows)
        #pragma unroll
        for (int ks = 0; ks < 2; ++ks) {
            bh8 pf = *(const bh8*)(pw + (unsigned)((c * 128 + ks * 64 + g * 16) ^ ((c & 7) << 4)));
            #pragma unroll
            for (int n = 0; n < 4; ++n) {
                int rr = n * 16 + c;
                bh8 vf = *(const bh8*)(vsm + (unsigned)((rr * 128 + ks * 64 + g * 16) ^ ((rr & 7) << 4)));
                o[n] = __builtin_amdgcn_mfma_f32_16x16x32_bf16(pf, vf, o[n], 0, 0, 0);
            }
        }
    }
    // ---- epilogue
    #pragma unroll
    for (int n = 0; n < 4; ++n) {
        #pragma unroll
        for (int j = 0; j < 4; ++j) {
            int qrow = q0 + wvi * 16 + g * 4 + j;
            out[((size_t)(b * LL + qrow)) * DD + h * DH + c + 16 * n] = o[n][j] / drow[j];
        }
    }
}

// ---------------------------------------------------------------- readm / mort heads
__global__ __launch_bounds__(64) void heads_k(
    const float* __restrict__ xn, const float* __restrict__ re_w, const float* __restrict__ re_b,
    const float* __restrict__ mo_w, const float* __restrict__ mo_b, float* __restrict__ out) {
    int lane = threadIdx.x;
    int b = blockIdx.x & 3;
    int which = blockIdx.x >> 2;
    const float* wv = which ? mo_w : re_w;
    const float* row = xn + (size_t)b * LL * DD;
    float s = 0.f;
    #pragma unroll
    for (int d = 0; d < DD / 64; ++d) s = fmaf(row[lane + d * 64], wv[lane + d * 64], s);
    #pragma unroll
    for (int o = 32; o >= 1; o >>= 1) s += __shfl_xor(s, o);
    if (lane == 0) out[(size_t)VV * BL + which * 4 + b] = s + (which ? mo_b[0] : re_b[0]);
}

// ================================================================ host
extern "C" void kernel_launch(void* const* d_in, const int* in_sizes, int n_in,
                              void* d_out, int out_size, void* d_ws, size_t ws_size,
                              hipStream_t stream) {
    const int*   ids      = (const int*)  d_in[0];
    const int*   typ      = (const int*)  d_in[1];
    const float* ts       = (const float*)d_in[2];
    const int*   amask    = (const int*)  d_in[3];
    const float* tok_emb  = (const float*)d_in[4];
    const float* type_emb = (const float*)d_in[5];
    const float* te_freq  = (const float*)d_in[6];
    const float* te_phase = (const float*)d_in[7];
    const float* te_w     = (const float*)d_in[8];
    const float* te_b     = (const float*)d_in[9];
    const float* m_norm_g = (const float*)d_in[10];
    const float* m_norm_b = (const float*)d_in[11];
    const float* m_in_w   = (const float*)d_in[12];
    const float* m_conv_w = (const float*)d_in[13];
    const float* m_conv_b = (const float*)d_in[14];
    const float* m_xproj  = (const float*)d_in[15];
    const float* m_dt_w   = (const float*)d_in[16];
    const float* m_dt_b   = (const float*)d_in[17];
    const float* m_Alog   = (const float*)d_in[18];
    const float* m_D      = (const float*)d_in[19];
    const float* m_out_w  = (const float*)d_in[20];
    const float* a_norm_g = (const float*)d_in[21];
    const float* a_norm_b = (const float*)d_in[22];
    const float* a_qkv_w  = (const float*)d_in[23];
    const float* a_out_w  = (const float*)d_in[24];
    const float* a_decay  = (const float*)d_in[25];
    const float* a_ffg    = (const float*)d_in[26];
    const float* a_ffb    = (const float*)d_in[27];
    const float* a_ff1    = (const float*)d_in[28];
    const float* a_ff2    = (const float*)d_in[29];
    const float* f_g      = (const float*)d_in[30];
    const float* f_b      = (const float*)d_in[31];
    const float* lm_w     = (const float*)d_in[32];
    const float* re_w     = (const float*)d_in[33];
    const float* re_b     = (const float*)d_in[34];
    const float* mo_w     = (const float*)d_in[35];
    const float* mo_b     = (const float*)d_in[36];

    float* out = (float*)d_out;
    float* ws  = (float*)d_ws;

    // workspace layout (floats)
    float* x   = ws;                          // BL*D
    float* xn  = x  + (size_t)BL * DD;        // BL*D
    float* t1  = xn + (size_t)BL * DD;        // BL*1024 (xz / qkv / ffh)
    float* t2  = t1 + (size_t)BL * 1024;      // BL*512  (xb conv out / attn out)
    float* t3  = t2 + (size_t)BL * DII;       // BL*512  (dt)
    float* t4  = t3 + (size_t)BL * DII;       // BL*512  (scan y)
    float* t5  = t4 + (size_t)BL * DII;       // BL*32   (B,C)
    float* sP  = t5 + (size_t)BL * 2 * SS;    // NC*B*DI*S (chunk a-products)
    float* sL  = sP + (size_t)NC * BB * DII * SS; // chunk locals -> h_init

    // 1. time features -> xn (scratch)
    feat_k<<<BL, 256, 0, stream>>>(ts, te_freq, te_phase, xn);
    // 2. enc = feat @ te_w^T + te_b -> x   (MFMA)
    mgemm_k<0, true, false><<<dim3(DD / 128, BL / 128), 256, 0, stream>>>(
        xn, te_w, te_b, nullptr, x, BL, DD, DD);
    // 3. x += tok_emb[ids] + type_emb[typ]
    embed_k<<<BL, 256, 0, stream>>>(x, ids, typ, tok_emb, type_emb);

    int mi = 0, ai = 0;
    for (int i = 0; i < 8; ++i) {
        if ((i + 1) % 4 == 0) {
            // ------------- attention block ai
            ln_k<<<BL, 256, 0, stream>>>(x, a_norm_g + ai * DD, a_norm_b + ai * DD, xn);
            mgemm_k<0, false, false><<<dim3((3 * DD) / 128, BL / 128), 256, 0, stream>>>(
                xn, a_qkv_w + (size_t)ai * 3 * DD * DD, nullptr, nullptr, t1, BL, 3 * DD, DD);
            fattn_k<<<BB * HH * (LL / 64), 256, 0, stream>>>(
                t1, ts, amask, a_decay + ai * HH, t2);
            mgemm_k<0, false, true><<<dim3(DD / 128, BL / 128), 256, 0, stream>>>(
                t2, a_out_w + (size_t)ai * DD * DD, nullptr, x, x, BL, DD, DD);
            ln_k<<<BL, 256, 0, stream>>>(x, a_ffg + ai * DD, a_ffb + ai * DD, xn);
            mgemm_k<1, false, false><<<dim3((4 * DD) / 128, BL / 128), 256, 0, stream>>>(
                xn, a_ff1 + (size_t)ai * 4 * DD * DD, nullptr, nullptr, t1, BL, 4 * DD, DD);
            mgemm_k<0, false, true><<<dim3(DD / 128, BL / 128), 256, 0, stream>>>(
                t1, a_ff2 + (size_t)ai * DD * 4 * DD, nullptr, x, x, BL, DD, 4 * DD);
            ++ai;
        } else {
            // ------------- mamba block mi
            ln_k<<<BL, 256, 0, stream>>>(x, m_norm_g + mi * DD, m_norm_b + mi * DD, xn);
            mgemm_k<0, false, false><<<dim3((2 * DII) / 128, BL / 128), 256, 0, stream>>>(
                xn, m_in_w + (size_t)mi * 2 * DII * DD, nullptr, nullptr, t1, BL, 2 * DII, DD);
            conv_k<<<(BL * DII) / 256, 256, 0, stream>>>(
                t1, m_conv_w + (size_t)mi * DII * DCC, m_conv_b + mi * DII, t2);
            gemm_k<0, false, false><<<dim3(1, BL / GBM), 256, 0, stream>>>(
                t2, m_xproj + (size_t)mi * 2 * SS * DII, nullptr, nullptr, t5, BL, 2 * SS, DII);
            mgemm_k<2, true, false><<<dim3(DII / 128, BL / 128), 256, 0, stream>>>(
                t2, m_dt_w + (size_t)mi * DII * DII, m_dt_b + mi * DII, nullptr, t3, BL, DII, DII);
            scanA_k<<<256, 256, 0, stream>>>(
                t3, t2, t5, m_Alog + (size_t)mi * DII * SS, sP, sL);
            scanB_k<<<8, 256, 0, stream>>>(sP, sL);
            scanC_k<<<256, 256, 0, stream>>>(
                t3, t2, t5, t1, m_Alog + (size_t)mi * DII * SS, m_D + mi * DII, sL, t4);
            mgemm_k<0, false, true><<<dim3(DD / 128, BL / 128), 256, 0, stream>>>(
                t4, m_out_w + (size_t)mi * DD * DII, nullptr, x, x, BL, DD, DII);
            ++mi;
        }
    }

    // final layernorm
    ln_k<<<BL, 256, 0, stream>>>(x, f_g, f_b, xn);
    // lm logits -> out[0 : BL*V]   (MFMA)
    mgemm_k<0, false, false><<<dim3(VV / 128, BL / 128), 256, 0, stream>>>(
        xn, lm_w, nullptr, nullptr, out, BL, VV, DD);
    // readm / mort heads
    heads_k<<<8, 64, 0, stream>>>(xn, re_w, re_b, mo_w, mo_b, out);
}

// Round 4
// 1511.556 us; speedup vs baseline: 8.2921x; 1.7790x over previous
//
#include <hip/hip_runtime.h>
#include <hip/hip_bf16.h>
#include <math.h>

// Problem constants
#define BB 4
#define LL 1024
#define BL (BB*LL)          // 4096 tokens
#define DD 256
#define VV 32000
#define HH 4
#define DH 64
#define SS 16
#define DCC 4
#define DII 512
#define NC 32               // scan chunks
#define CLN 32              // scan chunk length (NC*CLN == LL)

typedef float f32x4 __attribute__((ext_vector_type(4)));
typedef short bh8  __attribute__((ext_vector_type(8)));   // 8 bf16 (bit pattern)

__device__ __forceinline__ float sp_f(float x) {        // softplus
    return fmaxf(x, 0.f) + log1pf(expf(-fabsf(x)));
}
__device__ __forceinline__ float silu_f(float x) {
    return x / (1.f + expf(-x));
}
__device__ __forceinline__ short f2bf(float f) {
    __hip_bfloat16 h = __float2bfloat16(f);
    short s; __builtin_memcpy(&s, &h, 2); return s;
}
__device__ __forceinline__ bh8 pack8(float4 a, float4 b) {
    bh8 p;
    p[0] = f2bf(a.x); p[1] = f2bf(a.y); p[2] = f2bf(a.z); p[3] = f2bf(a.w);
    p[4] = f2bf(b.x); p[5] = f2bf(b.y); p[6] = f2bf(b.z); p[7] = f2bf(b.w);
    return p;
}

// ---------------------------------------------------------------- fp32 -> bf16 bulk convert
__global__ void cvt_k(const float* __restrict__ in, unsigned short* __restrict__ o, int n) {
    int i = (blockIdx.x * 256 + threadIdx.x) * 4;
    if (i >= n) return;
    float4 v = *(const float4*)(in + i);
    ushort4 u;
    u.x = (unsigned short)f2bf(v.x); u.y = (unsigned short)f2bf(v.y);
    u.z = (unsigned short)f2bf(v.z); u.w = (unsigned short)f2bf(v.w);
    *(ushort4*)(o + i) = u;
}

// ---------------------------------------------------------------- time feat
__global__ void feat_k(const float* __restrict__ ts, const float* __restrict__ freq,
                       const float* __restrict__ phase, float* __restrict__ feat) {
    int row = blockIdx.x, t = threadIdx.x;
    float tv = ts[row];
    int d = t & 127;
    float f = sp_f(freq[d]);
    float arg = tv * f + phase[d];
    feat[(size_t)row * DD + t] = (t < 128) ? sinf(arg) : cosf(arg);
}

// ---------------------------------------------------------------- embeddings
__global__ void embed_k(float* __restrict__ x, const int* __restrict__ ids,
                        const int* __restrict__ typ, const float* __restrict__ tok,
                        const float* __restrict__ tpe) {
    int row = blockIdx.x, t = threadIdx.x;
    x[(size_t)row * DD + t] += tok[(size_t)ids[row] * DD + t] + tpe[(size_t)typ[row] * DD + t];
}

// ---------------------------------------------------------------- layernorm (row of 256)
__global__ void ln_k(const float* __restrict__ x, const float* __restrict__ g,
                     const float* __restrict__ bbias, float* __restrict__ out) {
    __shared__ float red[8];
    int row = blockIdx.x, t = threadIdx.x;
    float v = x[(size_t)row * DD + t];
    float s = v;
    #pragma unroll
    for (int o = 32; o >= 1; o >>= 1) s += __shfl_xor(s, o);
    if ((t & 63) == 0) red[t >> 6] = s;
    __syncthreads();
    float mean = (red[0] + red[1] + red[2] + red[3]) * (1.f / 256.f);
    float d = v - mean;
    float s2 = d * d;
    #pragma unroll
    for (int o = 32; o >= 1; o >>= 1) s2 += __shfl_xor(s2, o);
    if ((t & 63) == 0) red[4 + (t >> 6)] = s2;
    __syncthreads();
    float var = (red[4] + red[5] + red[6] + red[7]) * (1.f / 256.f);
    out[(size_t)row * DD + t] = d * rsqrtf(var + 1e-5f) * g[t] + bbias[t];
}

// ---------------------------------------------------------------- 64x64-tile MFMA GEMM: out = A(MxK)@W(NxK)^T
// fp32 in (bf16-converted in staging), fp32 out. 4 waves, each a 32x32 quadrant.
// M%64==0, K%64==0 required; N bounds-checked (supports N=32 xproj).
template <int ACT, bool HASB, bool HASR>
__global__ __launch_bounds__(256) void mgemm64_k(
    const float* __restrict__ A, const float* __restrict__ W,
    const float* __restrict__ bias, const float* __restrict__ res,
    float* __restrict__ out, int M, int N, int K) {
    __shared__ __align__(16) char lds[16384];
    char* As = lds;
    char* Ws = lds + 8192;
    int tid = threadIdx.x;
    int bm = blockIdx.y * 64, bn = blockIdx.x * 64;
    int row = tid >> 2, q = tid & 3;          // staging: 64 rows x 4 quarters
    int lane = tid & 63, wv = tid >> 6;
    int wm = wv >> 1, wn = wv & 1;            // wave quadrant (32x32)
    int ro = lane & 15, kg = lane >> 4;

    f32x4 acc[2][2];
    #pragma unroll
    for (int i = 0; i < 2; ++i)
        #pragma unroll
        for (int j = 0; j < 2; ++j) acc[i][j] = (f32x4){0.f, 0.f, 0.f, 0.f};

    const float* ga = A + (size_t)(bm + row) * K + q * 16;
    const float* gw = W + (size_t)(bn + row) * K + q * 16;
    bool wvalid = (bn + row) < N;
    unsigned swb = (unsigned)(row * 128 + q * 32);
    unsigned sx  = (unsigned)((row & 7) << 4);

    for (int kk = 0; kk < K; kk += 64) {
        if (kk) __syncthreads();
        {
            float4 a0 = *(const float4*)(ga);
            float4 a1 = *(const float4*)(ga + 4);
            float4 a2 = *(const float4*)(ga + 8);
            float4 a3 = *(const float4*)(ga + 12);
            *(bh8*)(As + (swb ^ sx)) = pack8(a0, a1);
            *(bh8*)(As + ((swb + 16) ^ sx)) = pack8(a2, a3);
            float4 w0, w1, w2, w3;
            if (wvalid) {
                w0 = *(const float4*)(gw); w1 = *(const float4*)(gw + 4);
                w2 = *(const float4*)(gw + 8); w3 = *(const float4*)(gw + 12);
            } else {
                w0 = w1 = w2 = w3 = make_float4(0.f, 0.f, 0.f, 0.f);
            }
            *(bh8*)(Ws + (swb ^ sx)) = pack8(w0, w1);
            *(bh8*)(Ws + ((swb + 16) ^ sx)) = pack8(w2, w3);
        }
        ga += 64; gw += 64;
        __syncthreads();
        #pragma unroll
        for (int ks = 0; ks < 2; ++ks) {
            bh8 af[2], bf_[2];
            #pragma unroll
            for (int m = 0; m < 2; ++m) {
                int r = wm * 32 + m * 16 + ro;
                af[m] = *(const bh8*)(As + (unsigned)((r * 128 + ks * 64 + kg * 16) ^ ((r & 7) << 4)));
            }
            #pragma unroll
            for (int n = 0; n < 2; ++n) {
                int r = wn * 32 + n * 16 + ro;
                bf_[n] = *(const bh8*)(Ws + (unsigned)((r * 128 + ks * 64 + kg * 16) ^ ((r & 7) << 4)));
            }
            #pragma unroll
            for (int m = 0; m < 2; ++m)
                #pragma unroll
                for (int n = 0; n < 2; ++n)
                    acc[m][n] = __builtin_amdgcn_mfma_f32_16x16x32_bf16(af[m], bf_[n], acc[m][n], 0, 0, 0);
        }
    }

    int cr = (lane >> 4) * 4, cc = lane & 15;
    #pragma unroll
    for (int mf = 0; mf < 2; ++mf) {
        #pragma unroll
        for (int nf = 0; nf < 2; ++nf) {
            int n = bn + wn * 32 + nf * 16 + cc;
            if (n >= N) continue;
            int mbase = bm + wm * 32 + mf * 16 + cr;
            float bv = HASB ? bias[n] : 0.f;
            f32x4 a = acc[mf][nf];
            #pragma unroll
            for (int r = 0; r < 4; ++r) {
                float v = a[r] + bv;
                if (ACT == 1) v = silu_f(v);
                if (ACT == 2) v = sp_f(v);
                if (HASR) v += res[(size_t)(mbase + r) * N + n];
                out[(size_t)(mbase + r) * N + n] = v;
            }
        }
    }
}

// ---------------------------------------------------------------- lm-head GEMM: bf16 A and W, XCD-chunked
// grid (32, 256): lid%8 -> XCD, each XCD owns a contiguous 32-N-tile slab
// (2.1MB bf16 W + 2MB bf16 A ~= L2-resident). 128x128 tile, 4 waves.
__global__ __launch_bounds__(256) void mgemmL_k(
    const unsigned short* __restrict__ A, const unsigned short* __restrict__ W,
    float* __restrict__ out, int M, int N, int K) {
    __shared__ __align__(16) char lds[32768];
    char* As = lds;
    char* Ws = lds + 16384;
    int lid = blockIdx.y * 32 + blockIdx.x;
    int xcd = lid & 7, wk = lid >> 3;
    int nt = xcd * 32 + (wk >> 5);
    int mt = wk & 31;
    if (nt * 128 >= N) return;            // uniform early exit (no barrier yet)
    int bm = mt * 128, bn = nt * 128;

    int tid = threadIdx.x;
    int row = tid >> 1, half = tid & 1;
    int lane = tid & 63, wv = tid >> 6;
    int wm = wv >> 1, wn = wv & 1;
    int ro = lane & 15, kg = lane >> 4;

    f32x4 acc[4][4];
    #pragma unroll
    for (int i = 0; i < 4; ++i)
        #pragma unroll
        for (int j = 0; j < 4; ++j) acc[i][j] = (f32x4){0.f, 0.f, 0.f, 0.f};

    const unsigned short* ga = A + (size_t)(bm + row) * K + half * 32;
    const unsigned short* gw = W + (size_t)(bn + row) * K + half * 32;
    unsigned swb = (unsigned)(row * 128 + half * 64);
    unsigned sx  = (unsigned)((row & 7) << 4);

    for (int kk = 0; kk < K; kk += 64) {
        if (kk) __syncthreads();
        #pragma unroll
        for (int j = 0; j < 4; ++j) {
            *(bh8*)(As + ((swb + j * 16) ^ sx)) = *(const bh8*)(ga + j * 8);
            *(bh8*)(Ws + ((swb + j * 16) ^ sx)) = *(const bh8*)(gw + j * 8);
        }
        ga += 64; gw += 64;
        __syncthreads();
        #pragma unroll
        for (int ks = 0; ks < 2; ++ks) {
            bh8 af[4], bf_[4];
            #pragma unroll
            for (int m = 0; m < 4; ++m) {
                int r = wm * 64 + m * 16 + ro;
                af[m] = *(const bh8*)(As + (unsigned)((r * 128 + ks * 64 + kg * 16) ^ ((r & 7) << 4)));
            }
            #pragma unroll
            for (int n = 0; n < 4; ++n) {
                int r = wn * 64 + n * 16 + ro;
                bf_[n] = *(const bh8*)(Ws + (unsigned)((r * 128 + ks * 64 + kg * 16) ^ ((r & 7) << 4)));
            }
            #pragma unroll
            for (int m = 0; m < 4; ++m)
                #pragma unroll
                for (int n = 0; n < 4; ++n)
                    acc[m][n] = __builtin_amdgcn_mfma_f32_16x16x32_bf16(af[m], bf_[n], acc[m][n], 0, 0, 0);
        }
    }

    int cr = (lane >> 4) * 4, cc = lane & 15;
    #pragma unroll
    for (int mf = 0; mf < 4; ++mf) {
        #pragma unroll
        for (int nf = 0; nf < 4; ++nf) {
            int n = bn + wn * 64 + nf * 16 + cc;
            int mbase = bm + wm * 64 + mf * 16 + cr;
            f32x4 a = acc[mf][nf];
            #pragma unroll
            for (int r = 0; r < 4; ++r)
                out[(size_t)(mbase + r) * N + n] = a[r];
        }
    }
}

// ---------------------------------------------------------------- depthwise causal conv + silu
__global__ void conv_k(const float* __restrict__ xz, const float* __restrict__ w,
                       const float* __restrict__ cb, float* __restrict__ xb) {
    int idx = blockIdx.x * blockDim.x + threadIdx.x;  // BL*DI
    int c = idx & (DII - 1);
    int row = idx >> 9;
    int l = row & (LL - 1);
    int base = row - l;
    const float* wc = w + c * DCC;
    float s = cb[c];
    #pragma unroll
    for (int j = 0; j < DCC; ++j) {
        int ll = l - (DCC - 1) + j;
        if (ll >= 0) s = fmaf(wc[j], xz[((size_t)(base + ll)) * (2 * DII) + c], s);
    }
    xb[(size_t)idx] = silu_f(s);
}

// ---------------------------------------------------------------- chunked selective scan (A/B/C phases)
__global__ __launch_bounds__(256) void scanA_k(
    const float* __restrict__ dt, const float* __restrict__ xb,
    const float* __restrict__ bc, const float* __restrict__ Alog,
    float* __restrict__ P, float* __restrict__ Lc) {
    int bid = blockIdx.x;
    int b = bid >> 6;
    int c = (bid >> 1) & 31;
    int di = (bid & 1) * 256 + threadIdx.x;
    float A[SS], ap[SS], h[SS];
    #pragma unroll
    for (int s = 0; s < SS; ++s) { A[s] = -expf(Alog[di * SS + s]); ap[s] = 1.f; h[s] = 0.f; }
    for (int l = c * CLN; l < c * CLN + CLN; ++l) {
        size_t base = (size_t)b * LL + l;
        float dtv = dt[base * DII + di];
        float xv  = xb[base * DII + di];
        const float* Bt = bc + base * (2 * SS);
        float u = dtv * xv;
        #pragma unroll
        for (int s = 0; s < SS; ++s) {
            float a = expf(dtv * A[s]);
            ap[s] *= a;
            h[s] = fmaf(a, h[s], u * Bt[s]);
        }
    }
    size_t o = (((size_t)c * BB + b) * DII + di) * SS;
    #pragma unroll
    for (int j = 0; j < 4; ++j) {
        *(f32x4*)(P  + o + j * 4) = (f32x4){ap[j*4], ap[j*4+1], ap[j*4+2], ap[j*4+3]};
        *(f32x4*)(Lc + o + j * 4) = (f32x4){h[j*4],  h[j*4+1],  h[j*4+2],  h[j*4+3]};
    }
}

__global__ __launch_bounds__(256) void scanB_k(const float* __restrict__ P, float* __restrict__ Lc) {
    int t = blockIdx.x * 256 + threadIdx.x;   // 0..2047
    int b = t >> 9, di = t & (DII - 1);
    f32x4 h[4];
    #pragma unroll
    for (int j = 0; j < 4; ++j) h[j] = (f32x4){0.f, 0.f, 0.f, 0.f};
    for (int c = 0; c < NC; ++c) {
        size_t o = (((size_t)c * BB + b) * DII + di) * SS;
        #pragma unroll
        for (int j = 0; j < 4; ++j) {
            f32x4 p  = *(const f32x4*)(P  + o + j * 4);
            f32x4 lc = *(const f32x4*)(Lc + o + j * 4);
            *(f32x4*)(Lc + o + j * 4) = h[j];     // h_init for chunk c (in-place)
            h[j] = p * h[j] + lc;
        }
    }
}

__global__ __launch_bounds__(256) void scanC_k(
    const float* __restrict__ dt, const float* __restrict__ xb,
    const float* __restrict__ bc, const float* __restrict__ xz,
    const float* __restrict__ Alog, const float* __restrict__ Dp,
    const float* __restrict__ Hi, float* __restrict__ y) {
    int bid = blockIdx.x;
    int b = bid >> 6;
    int c = (bid >> 1) & 31;
    int di = (bid & 1) * 256 + threadIdx.x;
    float A[SS], h[SS];
    #pragma unroll
    for (int s = 0; s < SS; ++s) A[s] = -expf(Alog[di * SS + s]);
    size_t o = (((size_t)c * BB + b) * DII + di) * SS;
    #pragma unroll
    for (int s = 0; s < SS; ++s) h[s] = Hi[o + s];
    float Dv = Dp[di];
    for (int l = c * CLN; l < c * CLN + CLN; ++l) {
        size_t base = (size_t)b * LL + l;
        float dtv = dt[base * DII + di];
        float xv  = xb[base * DII + di];
        float zv  = xz[base * (2 * DII) + DII + di];
        const float* Bt = bc + base * (2 * SS);
        float u = dtv * xv;
        float acc = 0.f;
        #pragma unroll
        for (int s = 0; s < SS; ++s) {
            float a = expf(dtv * A[s]);
            h[s] = fmaf(a, h[s], u * Bt[s]);
            acc = fmaf(h[s], Bt[SS + s], acc);
        }
        y[base * DII + di] = fmaf(Dv, xv, acc) * silu_f(zv);
    }
}

// ---------------------------------------------------------------- flash attention (MFMA)
__global__ __launch_bounds__(256) void fattn_k(
    const float* __restrict__ qkv, const float* __restrict__ ts,
    const int* __restrict__ mask, const float* __restrict__ decay,
    float* __restrict__ out) {
    __shared__ __align__(16) char ksm[8192];
    __shared__ __align__(16) char vsm[8192];
    __shared__ __align__(16) char psm[8192];
    __shared__ float tsk[64];
    __shared__ int   msk[64];

    int tid = threadIdx.x;
    int lane = tid & 63, wvi = tid >> 6;
    int qt = blockIdx.x & 15;
    int h  = (blockIdx.x >> 4) & 3;
    int b  = blockIdx.x >> 6;
    int q0 = qt * 64;
    int g = lane >> 4, c = lane & 15;

    bh8 qf[2];
    {
        const float* qrow = qkv + ((size_t)(b * LL + q0 + wvi * 16 + c)) * (3 * DD) + h * DH;
        #pragma unroll
        for (int ks = 0; ks < 2; ++ks) {
            float4 a  = *(const float4*)(qrow + ks * 32 + g * 8);
            float4 bb = *(const float4*)(qrow + ks * 32 + g * 8 + 4);
            qf[ks] = pack8(a, bb);
        }
    }
    float tq[4];
    #pragma unroll
    for (int j = 0; j < 4; ++j) tq[j] = ts[b * LL + q0 + wvi * 16 + g * 4 + j];
    float spd = sp_f(decay[h]);

    f32x4 o[4];
    #pragma unroll
    for (int n = 0; n < 4; ++n) o[n] = (f32x4){0.f, 0.f, 0.f, 0.f};
    float mrow[4] = {-INFINITY, -INFINITY, -INFINITY, -INFINITY};
    float drow[4] = {0.f, 0.f, 0.f, 0.f};

    char* pw = psm + wvi * 2048;

    for (int kt = 0; kt <= qt; ++kt) {
        int k0 = kt * 64;
        __syncthreads();
        {
            int row = tid >> 2, qq = tid & 3;
            const float* kr = qkv + ((size_t)(b * LL + k0 + row)) * (3 * DD) + DD + h * DH + qq * 16;
            float4 k0v = *(const float4*)(kr);
            float4 k1v = *(const float4*)(kr + 4);
            float4 k2v = *(const float4*)(kr + 8);
            float4 k3v = *(const float4*)(kr + 12);
            unsigned sw = (unsigned)((row & 7) << 4);
            unsigned base = (unsigned)(row * 128 + qq * 32);
            *(bh8*)(ksm + (base ^ sw)) = pack8(k0v, k1v);
            *(bh8*)(ksm + ((base + 16) ^ sw)) = pack8(k2v, k3v);
            const float* vr = qkv + ((size_t)(b * LL + k0 + row)) * (3 * DD) + 2 * DD + h * DH + qq * 16;
            #pragma unroll
            for (int i = 0; i < 16; ++i) {
                int dh = qq * 16 + i;
                *(short*)(vsm + (unsigned)((dh * 128 + row * 2) ^ ((dh & 7) << 4))) = f2bf(vr[i]);
            }
            if (tid < 64) { tsk[tid] = ts[b * LL + k0 + tid]; msk[tid] = mask[b * LL + k0 + tid]; }
        }
        __syncthreads();

        f32x4 sf[4];
        #pragma unroll
        for (int n = 0; n < 4; ++n) sf[n] = (f32x4){0.f, 0.f, 0.f, 0.f};
        #pragma unroll
        for (int ks = 0; ks < 2; ++ks) {
            #pragma unroll
            for (int nf = 0; nf < 4; ++nf) {
                int rr = nf * 16 + c;
                bh8 kf = *(const bh8*)(ksm + (unsigned)((rr * 128 + ks * 64 + g * 16) ^ ((rr & 7) << 4)));
                sf[nf] = __builtin_amdgcn_mfma_f32_16x16x32_bf16(qf[ks], kf, sf[nf], 0, 0, 0);
            }
        }
        float mnew[4] = {mrow[0], mrow[1], mrow[2], mrow[3]};
        #pragma unroll
        for (int nf = 0; nf < 4; ++nf) {
            int kk = c + 16 * nf;
            float tk = tsk[kk];
            bool md = (msk[kk] == 0);
            #pragma unroll
            for (int j = 0; j < 4; ++j) {
                int qrow = q0 + wvi * 16 + g * 4 + j;
                float s = sf[nf][j] * 0.125f - spd * fabsf(tq[j] - tk) * (1.f / 24.f);
                bool dead = md || (k0 + kk > qrow);
                s = dead ? -INFINITY : s;
                sf[nf][j] = s;
                mnew[j] = fmaxf(mnew[j], s);
            }
        }
        #pragma unroll
        for (int off = 1; off <= 8; off <<= 1)
            #pragma unroll
            for (int j = 0; j < 4; ++j) mnew[j] = fmaxf(mnew[j], __shfl_xor(mnew[j], off));
        float scl[4], psum[4];
        #pragma unroll
        for (int j = 0; j < 4; ++j) {
            scl[j] = (mnew[j] == -INFINITY) ? 1.f : expf(mrow[j] - mnew[j]);
            psum[j] = 0.f;
            mrow[j] = mnew[j];
        }
        #pragma unroll
        for (int nf = 0; nf < 4; ++nf) {
            #pragma unroll
            for (int j = 0; j < 4; ++j) {
                float s = sf[nf][j];
                float p = (s == -INFINITY) ? 0.f : expf(s - mrow[j]);
                psum[j] += p;
                int row = g * 4 + j;
                *(short*)(pw + (unsigned)((row * 128 + (c + 16 * nf) * 2) ^ ((row & 7) << 4))) = f2bf(p);
            }
        }
        #pragma unroll
        for (int off = 1; off <= 8; off <<= 1)
            #pragma unroll
            for (int j = 0; j < 4; ++j) psum[j] += __shfl_xor(psum[j], off);
        #pragma unroll
        for (int j = 0; j < 4; ++j) drow[j] = drow[j] * scl[j] + psum[j];
        #pragma unroll
        for (int n = 0; n < 4; ++n)
            #pragma unroll
            for (int j = 0; j < 4; ++j) o[n][j] *= scl[j];
        #pragma unroll
        for (int ks = 0; ks < 2; ++ks) {
            bh8 pf = *(const bh8*)(pw + (unsigned)((c * 128 + ks * 64 + g * 16) ^ ((c & 7) << 4)));
            #pragma unroll
            for (int n = 0; n < 4; ++n) {
                int rr = n * 16 + c;
                bh8 vf = *(const bh8*)(vsm + (unsigned)((rr * 128 + ks * 64 + g * 16) ^ ((rr & 7) << 4)));
                o[n] = __builtin_amdgcn_mfma_f32_16x16x32_bf16(pf, vf, o[n], 0, 0, 0);
            }
        }
    }
    #pragma unroll
    for (int n = 0; n < 4; ++n) {
        #pragma unroll
        for (int j = 0; j < 4; ++j) {
            int qrow = q0 + wvi * 16 + g * 4 + j;
            out[((size_t)(b * LL + qrow)) * DD + h * DH + c + 16 * n] = o[n][j] / drow[j];
        }
    }
}

// ---------------------------------------------------------------- readm / mort heads
__global__ __launch_bounds__(64) void heads_k(
    const float* __restrict__ xn, const float* __restrict__ re_w, const float* __restrict__ re_b,
    const float* __restrict__ mo_w, const float* __restrict__ mo_b, float* __restrict__ out) {
    int lane = threadIdx.x;
    int b = blockIdx.x & 3;
    int which = blockIdx.x >> 2;
    const float* wv = which ? mo_w : re_w;
    const float* row = xn + (size_t)b * LL * DD;
    float s = 0.f;
    #pragma unroll
    for (int d = 0; d < DD / 64; ++d) s = fmaf(row[lane + d * 64], wv[lane + d * 64], s);
    #pragma unroll
    for (int o = 32; o >= 1; o >>= 1) s += __shfl_xor(s, o);
    if (lane == 0) out[(size_t)VV * BL + which * 4 + b] = s + (which ? mo_b[0] : re_b[0]);
}

// ================================================================ host
extern "C" void kernel_launch(void* const* d_in, const int* in_sizes, int n_in,
                              void* d_out, int out_size, void* d_ws, size_t ws_size,
                              hipStream_t stream) {
    const int*   ids      = (const int*)  d_in[0];
    const int*   typ      = (const int*)  d_in[1];
    const float* ts       = (const float*)d_in[2];
    const int*   amask    = (const int*)  d_in[3];
    const float* tok_emb  = (const float*)d_in[4];
    const float* type_emb = (const float*)d_in[5];
    const float* te_freq  = (const float*)d_in[6];
    const float* te_phase = (const float*)d_in[7];
    const float* te_w     = (const float*)d_in[8];
    const float* te_b     = (const float*)d_in[9];
    const float* m_norm_g = (const float*)d_in[10];
    const float* m_norm_b = (const float*)d_in[11];
    const float* m_in_w   = (const float*)d_in[12];
    const float* m_conv_w = (const float*)d_in[13];
    const float* m_conv_b = (const float*)d_in[14];
    const float* m_xproj  = (const float*)d_in[15];
    const float* m_dt_w   = (const float*)d_in[16];
    const float* m_dt_b   = (const float*)d_in[17];
    const float* m_Alog   = (const float*)d_in[18];
    const float* m_D      = (const float*)d_in[19];
    const float* m_out_w  = (const float*)d_in[20];
    const float* a_norm_g = (const float*)d_in[21];
    const float* a_norm_b = (const float*)d_in[22];
    const float* a_qkv_w  = (const float*)d_in[23];
    const float* a_out_w  = (const float*)d_in[24];
    const float* a_decay  = (const float*)d_in[25];
    const float* a_ffg    = (const float*)d_in[26];
    const float* a_ffb    = (const float*)d_in[27];
    const float* a_ff1    = (const float*)d_in[28];
    const float* a_ff2    = (const float*)d_in[29];
    const float* f_g      = (const float*)d_in[30];
    const float* f_b      = (const float*)d_in[31];
    const float* lm_w     = (const float*)d_in[32];
    const float* re_w     = (const float*)d_in[33];
    const float* re_b     = (const float*)d_in[34];
    const float* mo_w     = (const float*)d_in[35];
    const float* mo_b     = (const float*)d_in[36];

    float* out = (float*)d_out;
    float* ws  = (float*)d_ws;

    // workspace layout (floats)
    float* x   = ws;                          // BL*D
    float* xn  = x  + (size_t)BL * DD;        // BL*D
    float* t1  = xn + (size_t)BL * DD;        // BL*1024 (xz / qkv / ffh; aliased as bf16 lm_w at end)
    float* t2  = t1 + (size_t)BL * 1024;      // BL*512  (xb / attn out; aliased as bf16 xn at end)
    float* t3  = t2 + (size_t)BL * DII;       // BL*512  (dt)
    float* t4  = t3 + (size_t)BL * DII;       // BL*512  (scan y)
    float* t5  = t4 + (size_t)BL * DII;       // BL*32   (B,C)
    float* sP  = t5 + (size_t)BL * 2 * SS;    // NC*B*DI*S (chunk a-products)
    float* sL  = sP + (size_t)NC * BB * DII * SS; // chunk locals -> h_init

    // 1. time features -> xn (scratch)
    feat_k<<<BL, 256, 0, stream>>>(ts, te_freq, te_phase, xn);
    // 2. enc = feat @ te_w^T + te_b -> x
    mgemm64_k<0, true, false><<<dim3(DD / 64, BL / 64), 256, 0, stream>>>(
        xn, te_w, te_b, nullptr, x, BL, DD, DD);
    // 3. x += tok_emb[ids] + type_emb[typ]
    embed_k<<<BL, 256, 0, stream>>>(x, ids, typ, tok_emb, type_emb);

    int mi = 0, ai = 0;
    for (int i = 0; i < 8; ++i) {
        if ((i + 1) % 4 == 0) {
            // ------------- attention block ai
            ln_k<<<BL, 256, 0, stream>>>(x, a_norm_g + ai * DD, a_norm_b + ai * DD, xn);
            mgemm64_k<0, false, false><<<dim3((3 * DD) / 64, BL / 64), 256, 0, stream>>>(
                xn, a_qkv_w + (size_t)ai * 3 * DD * DD, nullptr, nullptr, t1, BL, 3 * DD, DD);
            fattn_k<<<BB * HH * (LL / 64), 256, 0, stream>>>(
                t1, ts, amask, a_decay + ai * HH, t2);
            mgemm64_k<0, false, true><<<dim3(DD / 64, BL / 64), 256, 0, stream>>>(
                t2, a_out_w + (size_t)ai * DD * DD, nullptr, x, x, BL, DD, DD);
            ln_k<<<BL, 256, 0, stream>>>(x, a_ffg + ai * DD, a_ffb + ai * DD, xn);
            mgemm64_k<1, false, false><<<dim3((4 * DD) / 64, BL / 64), 256, 0, stream>>>(
                xn, a_ff1 + (size_t)ai * 4 * DD * DD, nullptr, nullptr, t1, BL, 4 * DD, DD);
            mgemm64_k<0, false, true><<<dim3(DD / 64, BL / 64), 256, 0, stream>>>(
                t1, a_ff2 + (size_t)ai * DD * 4 * DD, nullptr, x, x, BL, DD, 4 * DD);
            ++ai;
        } else {
            // ------------- mamba block mi
            ln_k<<<BL, 256, 0, stream>>>(x, m_norm_g + mi * DD, m_norm_b + mi * DD, xn);
            mgemm64_k<0, false, false><<<dim3((2 * DII) / 64, BL / 64), 256, 0, stream>>>(
                xn, m_in_w + (size_t)mi * 2 * DII * DD, nullptr, nullptr, t1, BL, 2 * DII, DD);
            conv_k<<<(BL * DII) / 256, 256, 0, stream>>>(
                t1, m_conv_w + (size_t)mi * DII * DCC, m_conv_b + mi * DII, t2);
            mgemm64_k<0, false, false><<<dim3(1, BL / 64), 256, 0, stream>>>(
                t2, m_xproj + (size_t)mi * 2 * SS * DII, nullptr, nullptr, t5, BL, 2 * SS, DII);
            mgemm64_k<2, true, false><<<dim3(DII / 64, BL / 64), 256, 0, stream>>>(
                t2, m_dt_w + (size_t)mi * DII * DII, m_dt_b + mi * DII, nullptr, t3, BL, DII, DII);
            scanA_k<<<256, 256, 0, stream>>>(
                t3, t2, t5, m_Alog + (size_t)mi * DII * SS, sP, sL);
            scanB_k<<<8, 256, 0, stream>>>(sP, sL);
            scanC_k<<<256, 256, 0, stream>>>(
                t3, t2, t5, t1, m_Alog + (size_t)mi * DII * SS, m_D + mi * DII, sL, t4);
            mgemm64_k<0, false, true><<<dim3(DD / 64, BL / 64), 256, 0, stream>>>(
                t4, m_out_w + (size_t)mi * DD * DII, nullptr, x, x, BL, DD, DII);
            ++mi;
        }
    }

    // final layernorm
    ln_k<<<BL, 256, 0, stream>>>(x, f_g, f_b, xn);
    // bf16 conversions into freed t1/t2 regions
    unsigned short* wbf = (unsigned short*)t1;   // 32000*256 bf16 = 16.4MB (< t1 16.8MB)
    unsigned short* abf = (unsigned short*)t2;   // 4096*256 bf16 = 2.1MB
    cvt_k<<<(VV * DD / 4 + 255) / 256, 256, 0, stream>>>(lm_w, wbf, VV * DD);
    cvt_k<<<(BL * DD / 4 + 255) / 256, 256, 0, stream>>>(xn, abf, BL * DD);
    // lm logits -> out[0 : BL*V]   (XCD-chunked MFMA)
    mgemmL_k<<<dim3(32, 256), 256, 0, stream>>>(abf, wbf, out, BL, VV, DD);
    // readm / mort heads
    heads_k<<<8, 64, 0, stream>>>(xn, re_w, re_b, mo_w, mo_b, out);
}

// Round 5
// 1496.409 us; speedup vs baseline: 8.3761x; 1.0101x over previous
//
#include <hip/hip_runtime.h>
#include <hip/hip_bf16.h>
#include <math.h>

// Problem constants
#define BB 4
#define LL 1024
#define BL (BB*LL)          // 4096 tokens
#define DD 256
#define VV 32000
#define HH 4
#define DH 64
#define SS 16
#define DCC 4
#define DII 512

typedef float f32x4 __attribute__((ext_vector_type(4)));
typedef short bh8  __attribute__((ext_vector_type(8)));   // 8 bf16 (bit pattern)
typedef unsigned short u16;

__device__ __forceinline__ float sp_f(float x) {        // softplus
    return fmaxf(x, 0.f) + log1pf(expf(-fabsf(x)));
}
__device__ __forceinline__ float silu_f(float x) {
    return x / (1.f + expf(-x));
}
__device__ __forceinline__ short f2bf(float f) {
    __hip_bfloat16 h = __float2bfloat16(f);
    short s; __builtin_memcpy(&s, &h, 2); return s;
}
__device__ __forceinline__ float bf2f(u16 u) {
    unsigned v = ((unsigned)u) << 16;
    float f; __builtin_memcpy(&f, &v, 4); return f;
}
__device__ __forceinline__ bh8 pack8(float4 a, float4 b) {
    bh8 p;
    p[0] = f2bf(a.x); p[1] = f2bf(a.y); p[2] = f2bf(a.z); p[3] = f2bf(a.w);
    p[4] = f2bf(b.x); p[5] = f2bf(b.y); p[6] = f2bf(b.z); p[7] = f2bf(b.w);
    return p;
}

// ---------------------------------------------------------------- fp32 -> bf16 bulk convert
__global__ void cvt_k(const float* __restrict__ in, u16* __restrict__ o, int n) {
    int i = (blockIdx.x * 256 + threadIdx.x) * 4;
    if (i >= n) return;
    float4 v = *(const float4*)(in + i);
    ushort4 u;
    u.x = (u16)f2bf(v.x); u.y = (u16)f2bf(v.y);
    u.z = (u16)f2bf(v.z); u.w = (u16)f2bf(v.w);
    *(ushort4*)(o + i) = u;
}

// ---------------------------------------------------------------- all-weights fp32->bf16 (one pass)
// wbuf layout (bf16 elems):
//  te_w    [0,        65536)
//  a_qkv   [65536,    458752)
//  a_out   [458752,   589824)
//  a_ff1   [589824,   1114112)
//  a_ff2   [1114112,  1638400)
//  m_in    [1638400,  3211264)
//  m_out   [3211264,  3997696)
//  m_dtx   [3997696,  5668864)  per layer 278528: rows 0..511 dt_w, 512..543 xproj
#define WB_TOT 5668864
__global__ void cvtall_k(const float* __restrict__ te_w, const float* __restrict__ a_qkv,
                         const float* __restrict__ a_out, const float* __restrict__ a_ff1,
                         const float* __restrict__ a_ff2, const float* __restrict__ m_in,
                         const float* __restrict__ m_out, const float* __restrict__ m_dt,
                         const float* __restrict__ m_xp, u16* __restrict__ dst) {
    long i = ((long)blockIdx.x * 256 + threadIdx.x) * 4;
    if (i >= WB_TOT) return;
    const float* src; long off;
    if      (i < 65536)   { src = te_w;  off = i; }
    else if (i < 458752)  { src = a_qkv; off = i - 65536; }
    else if (i < 589824)  { src = a_out; off = i - 458752; }
    else if (i < 1114112) { src = a_ff1; off = i - 589824; }
    else if (i < 1638400) { src = a_ff2; off = i - 1114112; }
    else if (i < 3211264) { src = m_in;  off = i - 1638400; }
    else if (i < 3997696) { src = m_out; off = i - 3211264; }
    else {
        long l = i - 3997696;
        int mi = (int)(l / 278528);
        long r = l - (long)mi * 278528;
        if (r < 262144) { src = m_dt + (long)mi * 262144; off = r; }
        else            { src = m_xp + (long)mi * 16384;  off = r - 262144; }
    }
    float4 v = *(const float4*)(src + off);
    ushort4 u;
    u.x = (u16)f2bf(v.x); u.y = (u16)f2bf(v.y);
    u.z = (u16)f2bf(v.z); u.w = (u16)f2bf(v.w);
    *(ushort4*)(dst + i) = u;
}

// ---------------------------------------------------------------- time feat (bf16 out)
__global__ void feat_k(const float* __restrict__ ts, const float* __restrict__ freq,
                       const float* __restrict__ phase, u16* __restrict__ feat) {
    int row = blockIdx.x, t = threadIdx.x;
    float tv = ts[row];
    int d = t & 127;
    float f = sp_f(freq[d]);
    float arg = tv * f + phase[d];
    feat[(size_t)row * DD + t] = (u16)f2bf((t < 128) ? sinf(arg) : cosf(arg));
}

// ---------------------------------------------------------------- embeddings
__global__ void embed_k(float* __restrict__ x, const int* __restrict__ ids,
                        const int* __restrict__ typ, const float* __restrict__ tok,
                        const float* __restrict__ tpe) {
    int row = blockIdx.x, t = threadIdx.x;
    x[(size_t)row * DD + t] += tok[(size_t)ids[row] * DD + t] + tpe[(size_t)typ[row] * DD + t];
}

// ---------------------------------------------------------------- layernorm (bf16 out)
__global__ void ln_k(const float* __restrict__ x, const float* __restrict__ g,
                     const float* __restrict__ bbias, u16* __restrict__ out) {
    __shared__ float red[8];
    int row = blockIdx.x, t = threadIdx.x;
    float v = x[(size_t)row * DD + t];
    float s = v;
    #pragma unroll
    for (int o = 32; o >= 1; o >>= 1) s += __shfl_xor(s, o);
    if ((t & 63) == 0) red[t >> 6] = s;
    __syncthreads();
    float mean = (red[0] + red[1] + red[2] + red[3]) * (1.f / 256.f);
    float d = v - mean;
    float s2 = d * d;
    #pragma unroll
    for (int o = 32; o >= 1; o >>= 1) s2 += __shfl_xor(s2, o);
    if ((t & 63) == 0) red[4 + (t >> 6)] = s2;
    __syncthreads();
    float var = (red[4] + red[5] + red[6] + red[7]) * (1.f / 256.f);
    out[(size_t)row * DD + t] = (u16)f2bf(d * rsqrtf(var + 1e-5f) * g[t] + bbias[t]);
}

// ---------------------------------------------------------------- 64x64-tile MFMA GEMM, bf16 A and W
// ACT: 0 none, 1 silu, 3 dtx-mode (n<512: softplus+bias -> out; else raw -> out2)
// BOUT: write bf16 output. M%64==0, K%64==0; N bounds-checked.
template <int ACT, bool HASB, bool HASR, bool BOUT>
__global__ __launch_bounds__(256) void bgemm_k(
    const u16* __restrict__ A, const u16* __restrict__ W,
    const float* __restrict__ bias, const float* __restrict__ res,
    void* __restrict__ outv, float* __restrict__ out2, int M, int N, int K) {
    __shared__ __align__(16) char lds[16384];
    char* As = lds;
    char* Ws = lds + 8192;
    int tid = threadIdx.x;
    int bm = blockIdx.y * 64, bn = blockIdx.x * 64;
    int row = tid >> 2, q = tid & 3;          // staging: 64 rows x 4 quarters (16 bf16 each)
    int lane = tid & 63, wv = tid >> 6;
    int wm = wv >> 1, wn = wv & 1;            // wave quadrant (32x32)
    int ro = lane & 15, kg = lane >> 4;

    f32x4 acc[2][2];
    #pragma unroll
    for (int i = 0; i < 2; ++i)
        #pragma unroll
        for (int j = 0; j < 2; ++j) acc[i][j] = (f32x4){0.f, 0.f, 0.f, 0.f};

    const u16* ga = A + (size_t)(bm + row) * K + q * 16;
    const u16* gw = W + (size_t)(bn + row) * K + q * 16;
    bool wvalid = (bn + row) < N;
    unsigned swb = (unsigned)(row * 128 + q * 32);
    unsigned sx  = (unsigned)((row & 7) << 4);

    for (int kk = 0; kk < K; kk += 64) {
        if (kk) __syncthreads();
        {
            bh8 a0 = *(const bh8*)(ga);
            bh8 a1 = *(const bh8*)(ga + 8);
            *(bh8*)(As + (swb ^ sx)) = a0;
            *(bh8*)(As + ((swb + 16) ^ sx)) = a1;
            bh8 w0 = {}, w1 = {};
            if (wvalid) { w0 = *(const bh8*)(gw); w1 = *(const bh8*)(gw + 8); }
            *(bh8*)(Ws + (swb ^ sx)) = w0;
            *(bh8*)(Ws + ((swb + 16) ^ sx)) = w1;
        }
        ga += 64; gw += 64;
        __syncthreads();
        #pragma unroll
        for (int ks = 0; ks < 2; ++ks) {
            bh8 af[2], bf_[2];
            #pragma unroll
            for (int m = 0; m < 2; ++m) {
                int r = wm * 32 + m * 16 + ro;
                af[m] = *(const bh8*)(As + (unsigned)((r * 128 + ks * 64 + kg * 16) ^ ((r & 7) << 4)));
            }
            #pragma unroll
            for (int n = 0; n < 2; ++n) {
                int r = wn * 32 + n * 16 + ro;
                bf_[n] = *(const bh8*)(Ws + (unsigned)((r * 128 + ks * 64 + kg * 16) ^ ((r & 7) << 4)));
            }
            #pragma unroll
            for (int m = 0; m < 2; ++m)
                #pragma unroll
                for (int n = 0; n < 2; ++n)
                    acc[m][n] = __builtin_amdgcn_mfma_f32_16x16x32_bf16(af[m], bf_[n], acc[m][n], 0, 0, 0);
        }
    }

    float* outf = (float*)outv;
    u16*   outb = (u16*)outv;
    int cr = (lane >> 4) * 4, cc = lane & 15;
    #pragma unroll
    for (int mf = 0; mf < 2; ++mf) {
        #pragma unroll
        for (int nf = 0; nf < 2; ++nf) {
            int n = bn + wn * 32 + nf * 16 + cc;
            if (n >= N) continue;
            int mbase = bm + wm * 32 + mf * 16 + cr;
            f32x4 a = acc[mf][nf];
            #pragma unroll
            for (int r = 0; r < 4; ++r) {
                float v = a[r];
                int m = mbase + r;
                if (ACT == 3) {
                    if (n < 512) outf[(size_t)m * 512 + n] = sp_f(v + bias[n]);
                    else         out2[(size_t)m * 32 + (n - 512)] = v;
                } else {
                    if (HASB) v += bias[n];
                    if (ACT == 1) v = silu_f(v);
                    if (HASR) v += res[(size_t)m * N + n];
                    if (BOUT) outb[(size_t)m * N + n] = (u16)f2bf(v);
                    else      outf[(size_t)m * N + n] = v;
                }
            }
        }
    }
}

// ---------------------------------------------------------------- lm-head GEMM: bf16 A and W, XCD-chunked
__global__ __launch_bounds__(256) void mgemmL_k(
    const u16* __restrict__ A, const u16* __restrict__ W,
    float* __restrict__ out, int M, int N, int K) {
    __shared__ __align__(16) char lds[32768];
    char* As = lds;
    char* Ws = lds + 16384;
    int lid = blockIdx.y * 32 + blockIdx.x;
    int xcd = lid & 7, wk = lid >> 3;
    int nt = xcd * 32 + (wk >> 5);
    int mt = wk & 31;
    if (nt * 128 >= N) return;            // uniform early exit (before any barrier)
    int bm = mt * 128, bn = nt * 128;

    int tid = threadIdx.x;
    int row = tid >> 1, half = tid & 1;
    int lane = tid & 63, wv = tid >> 6;
    int wm = wv >> 1, wn = wv & 1;
    int ro = lane & 15, kg = lane >> 4;

    f32x4 acc[4][4];
    #pragma unroll
    for (int i = 0; i < 4; ++i)
        #pragma unroll
        for (int j = 0; j < 4; ++j) acc[i][j] = (f32x4){0.f, 0.f, 0.f, 0.f};

    const u16* ga = A + (size_t)(bm + row) * K + half * 32;
    const u16* gw = W + (size_t)(bn + row) * K + half * 32;
    unsigned swb = (unsigned)(row * 128 + half * 64);
    unsigned sx  = (unsigned)((row & 7) << 4);

    for (int kk = 0; kk < K; kk += 64) {
        if (kk) __syncthreads();
        #pragma unroll
        for (int j = 0; j < 4; ++j) {
            *(bh8*)(As + ((swb + j * 16) ^ sx)) = *(const bh8*)(ga + j * 8);
            *(bh8*)(Ws + ((swb + j * 16) ^ sx)) = *(const bh8*)(gw + j * 8);
        }
        ga += 64; gw += 64;
        __syncthreads();
        #pragma unroll
        for (int ks = 0; ks < 2; ++ks) {
            bh8 af[4], bf_[4];
            #pragma unroll
            for (int m = 0; m < 4; ++m) {
                int r = wm * 64 + m * 16 + ro;
                af[m] = *(const bh8*)(As + (unsigned)((r * 128 + ks * 64 + kg * 16) ^ ((r & 7) << 4)));
            }
            #pragma unroll
            for (int n = 0; n < 4; ++n) {
                int r = wn * 64 + n * 16 + ro;
                bf_[n] = *(const bh8*)(Ws + (unsigned)((r * 128 + ks * 64 + kg * 16) ^ ((r & 7) << 4)));
            }
            #pragma unroll
            for (int m = 0; m < 4; ++m)
                #pragma unroll
                for (int n = 0; n < 4; ++n)
                    acc[m][n] = __builtin_amdgcn_mfma_f32_16x16x32_bf16(af[m], bf_[n], acc[m][n], 0, 0, 0);
        }
    }

    int cr = (lane >> 4) * 4, cc = lane & 15;
    #pragma unroll
    for (int mf = 0; mf < 4; ++mf) {
        #pragma unroll
        for (int nf = 0; nf < 4; ++nf) {
            int n = bn + wn * 64 + nf * 16 + cc;
            int mbase = bm + wm * 64 + mf * 16 + cr;
            f32x4 a = acc[mf][nf];
            #pragma unroll
            for (int r = 0; r < 4; ++r)
                out[(size_t)(mbase + r) * N + n] = a[r];
        }
    }
}

// ---------------------------------------------------------------- depthwise causal conv + silu (fp32 + bf16 out)
__global__ void conv_k(const float* __restrict__ xz, const float* __restrict__ w,
                       const float* __restrict__ cb, float* __restrict__ xb,
                       u16* __restrict__ xbb) {
    int idx = blockIdx.x * blockDim.x + threadIdx.x;  // BL*DI
    int c = idx & (DII - 1);
    int row = idx >> 9;
    int l = row & (LL - 1);
    int base = row - l;
    const float* wc = w + c * DCC;
    float s = cb[c];
    #pragma unroll
    for (int j = 0; j < DCC; ++j) {
        int ll = l - (DCC - 1) + j;
        if (ll >= 0) s = fmaf(wc[j], xz[((size_t)(base + ll)) * (2 * DII) + c], s);
    }
    float v = silu_f(s);
    xb[(size_t)idx] = v;
    xbb[(size_t)idx] = (u16)f2bf(v);
}

// ---------------------------------------------------------------- chunked selective scan (A/B/C), runtime nc
__global__ __launch_bounds__(256) void scanA_k(
    const float* __restrict__ dt, const float* __restrict__ xb,
    const float* __restrict__ bc, const float* __restrict__ Alog,
    float* __restrict__ P, float* __restrict__ Lc, int nc, int cln) {
    int bid = blockIdx.x;
    int per_b = nc * 2;
    int b = bid / per_b;
    int rem = bid - b * per_b;
    int c = rem >> 1;
    int di = (rem & 1) * 256 + threadIdx.x;
    float A[SS], ap[SS], h[SS];
    #pragma unroll
    for (int s = 0; s < SS; ++s) { A[s] = -expf(Alog[di * SS + s]); ap[s] = 1.f; h[s] = 0.f; }
    for (int l = c * cln; l < c * cln + cln; ++l) {
        size_t base = (size_t)b * LL + l;
        float dtv = dt[base * DII + di];
        float xv  = xb[base * DII + di];
        const float* Bt = bc + base * (2 * SS);
        float u = dtv * xv;
        #pragma unroll
        for (int s = 0; s < SS; ++s) {
            float a = expf(dtv * A[s]);
            ap[s] *= a;
            h[s] = fmaf(a, h[s], u * Bt[s]);
        }
    }
    size_t o = (((size_t)c * BB + b) * DII + di) * SS;
    #pragma unroll
    for (int j = 0; j < 4; ++j) {
        *(f32x4*)(P  + o + j * 4) = (f32x4){ap[j*4], ap[j*4+1], ap[j*4+2], ap[j*4+3]};
        *(f32x4*)(Lc + o + j * 4) = (f32x4){h[j*4],  h[j*4+1],  h[j*4+2],  h[j*4+3]};
    }
}

__global__ __launch_bounds__(256) void scanB_k(const float* __restrict__ P, float* __restrict__ Lc, int nc) {
    int t = blockIdx.x * 256 + threadIdx.x;   // 0..2047
    int b = t >> 9, di = t & (DII - 1);
    f32x4 h[4];
    #pragma unroll
    for (int j = 0; j < 4; ++j) h[j] = (f32x4){0.f, 0.f, 0.f, 0.f};
    for (int c = 0; c < nc; ++c) {
        size_t o = (((size_t)c * BB + b) * DII + di) * SS;
        #pragma unroll
        for (int j = 0; j < 4; ++j) {
            f32x4 p  = *(const f32x4*)(P  + o + j * 4);
            f32x4 lc = *(const f32x4*)(Lc + o + j * 4);
            *(f32x4*)(Lc + o + j * 4) = h[j];     // h_init for chunk c (in-place)
            h[j] = p * h[j] + lc;
        }
    }
}

__global__ __launch_bounds__(256) void scanC_k(
    const float* __restrict__ dt, const float* __restrict__ xb,
    const float* __restrict__ bc, const float* __restrict__ xz,
    const float* __restrict__ Alog, const float* __restrict__ Dp,
    const float* __restrict__ Hi, u16* __restrict__ y, int nc, int cln) {
    int bid = blockIdx.x;
    int per_b = nc * 2;
    int b = bid / per_b;
    int rem = bid - b * per_b;
    int c = rem >> 1;
    int di = (rem & 1) * 256 + threadIdx.x;
    float A[SS], h[SS];
    #pragma unroll
    for (int s = 0; s < SS; ++s) A[s] = -expf(Alog[di * SS + s]);
    size_t o = (((size_t)c * BB + b) * DII + di) * SS;
    #pragma unroll
    for (int s = 0; s < SS; ++s) h[s] = Hi[o + s];
    float Dv = Dp[di];
    for (int l = c * cln; l < c * cln + cln; ++l) {
        size_t base = (size_t)b * LL + l;
        float dtv = dt[base * DII + di];
        float xv  = xb[base * DII + di];
        float zv  = xz[base * (2 * DII) + DII + di];
        const float* Bt = bc + base * (2 * SS);
        float u = dtv * xv;
        float acc = 0.f;
        #pragma unroll
        for (int s = 0; s < SS; ++s) {
            float a = expf(dtv * A[s]);
            h[s] = fmaf(a, h[s], u * Bt[s]);
            acc = fmaf(h[s], Bt[SS + s], acc);
        }
        y[base * DII + di] = (u16)f2bf(fmaf(Dv, xv, acc) * silu_f(zv));
    }
}

// ---------------------------------------------------------------- flash attention (MFMA), bf16 out
__global__ __launch_bounds__(256) void fattn_k(
    const float* __restrict__ qkv, const float* __restrict__ ts,
    const int* __restrict__ mask, const float* __restrict__ decay,
    u16* __restrict__ out) {
    __shared__ __align__(16) char ksm[8192];
    __shared__ __align__(16) char vsm[8192];
    __shared__ __align__(16) char psm[8192];
    __shared__ float tsk[64];
    __shared__ int   msk[64];

    int tid = threadIdx.x;
    int lane = tid & 63, wvi = tid >> 6;
    int qt = blockIdx.x & 15;
    int h  = (blockIdx.x >> 4) & 3;
    int b  = blockIdx.x >> 6;
    int q0 = qt * 64;
    int g = lane >> 4, c = lane & 15;

    bh8 qf[2];
    {
        const float* qrow = qkv + ((size_t)(b * LL + q0 + wvi * 16 + c)) * (3 * DD) + h * DH;
        #pragma unroll
        for (int ks = 0; ks < 2; ++ks) {
            float4 a  = *(const float4*)(qrow + ks * 32 + g * 8);
            float4 bb = *(const float4*)(qrow + ks * 32 + g * 8 + 4);
            qf[ks] = pack8(a, bb);
        }
    }
    float tq[4];
    #pragma unroll
    for (int j = 0; j < 4; ++j) tq[j] = ts[b * LL + q0 + wvi * 16 + g * 4 + j];
    float spd = sp_f(decay[h]);

    f32x4 o[4];
    #pragma unroll
    for (int n = 0; n < 4; ++n) o[n] = (f32x4){0.f, 0.f, 0.f, 0.f};
    float mrow[4] = {-INFINITY, -INFINITY, -INFINITY, -INFINITY};
    float drow[4] = {0.f, 0.f, 0.f, 0.f};

    char* pw = psm + wvi * 2048;

    for (int kt = 0; kt <= qt; ++kt) {
        int k0 = kt * 64;
        __syncthreads();
        {
            int row = tid >> 2, qq = tid & 3;
            const float* kr = qkv + ((size_t)(b * LL + k0 + row)) * (3 * DD) + DD + h * DH + qq * 16;
            float4 k0v = *(const float4*)(kr);
            float4 k1v = *(const float4*)(kr + 4);
            float4 k2v = *(const float4*)(kr + 8);
            float4 k3v = *(const float4*)(kr + 12);
            unsigned sw = (unsigned)((row & 7) << 4);
            unsigned base = (unsigned)(row * 128 + qq * 32);
            *(bh8*)(ksm + (base ^ sw)) = pack8(k0v, k1v);
            *(bh8*)(ksm + ((base + 16) ^ sw)) = pack8(k2v, k3v);
            const float* vr = qkv + ((size_t)(b * LL + k0 + row)) * (3 * DD) + 2 * DD + h * DH + qq * 16;
            #pragma unroll
            for (int i = 0; i < 16; ++i) {
                int dh = qq * 16 + i;
                *(short*)(vsm + (unsigned)((dh * 128 + row * 2) ^ ((dh & 7) << 4))) = f2bf(vr[i]);
            }
            if (tid < 64) { tsk[tid] = ts[b * LL + k0 + tid]; msk[tid] = mask[b * LL + k0 + tid]; }
        }
        __syncthreads();

        f32x4 sf[4];
        #pragma unroll
        for (int n = 0; n < 4; ++n) sf[n] = (f32x4){0.f, 0.f, 0.f, 0.f};
        #pragma unroll
        for (int ks = 0; ks < 2; ++ks) {
            #pragma unroll
            for (int nf = 0; nf < 4; ++nf) {
                int rr = nf * 16 + c;
                bh8 kf = *(const bh8*)(ksm + (unsigned)((rr * 128 + ks * 64 + g * 16) ^ ((rr & 7) << 4)));
                sf[nf] = __builtin_amdgcn_mfma_f32_16x16x32_bf16(qf[ks], kf, sf[nf], 0, 0, 0);
            }
        }
        float mnew[4] = {mrow[0], mrow[1], mrow[2], mrow[3]};
        #pragma unroll
        for (int nf = 0; nf < 4; ++nf) {
            int kk = c + 16 * nf;
            float tk = tsk[kk];
            bool md = (msk[kk] == 0);
            #pragma unroll
            for (int j = 0; j < 4; ++j) {
                int qrow = q0 + wvi * 16 + g * 4 + j;
                float s = sf[nf][j] * 0.125f - spd * fabsf(tq[j] - tk) * (1.f / 24.f);
                bool dead = md || (k0 + kk > qrow);
                s = dead ? -INFINITY : s;
                sf[nf][j] = s;
                mnew[j] = fmaxf(mnew[j], s);
            }
        }
        #pragma unroll
        for (int off = 1; off <= 8; off <<= 1)
            #pragma unroll
            for (int j = 0; j < 4; ++j) mnew[j] = fmaxf(mnew[j], __shfl_xor(mnew[j], off));
        float scl[4], psum[4];
        #pragma unroll
        for (int j = 0; j < 4; ++j) {
            scl[j] = (mnew[j] == -INFINITY) ? 1.f : expf(mrow[j] - mnew[j]);
            psum[j] = 0.f;
            mrow[j] = mnew[j];
        }
        #pragma unroll
        for (int nf = 0; nf < 4; ++nf) {
            #pragma unroll
            for (int j = 0; j < 4; ++j) {
                float s = sf[nf][j];
                float p = (s == -INFINITY) ? 0.f : expf(s - mrow[j]);
                psum[j] += p;
                int row = g * 4 + j;
                *(short*)(pw + (unsigned)((row * 128 + (c + 16 * nf) * 2) ^ ((row & 7) << 4))) = f2bf(p);
            }
        }
        #pragma unroll
        for (int off = 1; off <= 8; off <<= 1)
            #pragma unroll
            for (int j = 0; j < 4; ++j) psum[j] += __shfl_xor(psum[j], off);
        #pragma unroll
        for (int j = 0; j < 4; ++j) drow[j] = drow[j] * scl[j] + psum[j];
        #pragma unroll
        for (int n = 0; n < 4; ++n)
            #pragma unroll
            for (int j = 0; j < 4; ++j) o[n][j] *= scl[j];
        #pragma unroll
        for (int ks = 0; ks < 2; ++ks) {
            bh8 pf = *(const bh8*)(pw + (unsigned)((c * 128 + ks * 64 + g * 16) ^ ((c & 7) << 4)));
            #pragma unroll
            for (int n = 0; n < 4; ++n) {
                int rr = n * 16 + c;
                bh8 vf = *(const bh8*)(vsm + (unsigned)((rr * 128 + ks * 64 + g * 16) ^ ((rr & 7) << 4)));
                o[n] = __builtin_amdgcn_mfma_f32_16x16x32_bf16(pf, vf, o[n], 0, 0, 0);
            }
        }
    }
    #pragma unroll
    for (int n = 0; n < 4; ++n) {
        #pragma unroll
        for (int j = 0; j < 4; ++j) {
            int qrow = q0 + wvi * 16 + g * 4 + j;
            out[((size_t)(b * LL + qrow)) * DD + h * DH + c + 16 * n] = (u16)f2bf(o[n][j] / drow[j]);
        }
    }
}

// ---------------------------------------------------------------- readm / mort heads (bf16 xn)
__global__ __launch_bounds__(64) void heads_k(
    const u16* __restrict__ xn, const float* __restrict__ re_w, const float* __restrict__ re_b,
    const float* __restrict__ mo_w, const float* __restrict__ mo_b, float* __restrict__ out) {
    int lane = threadIdx.x;
    int b = blockIdx.x & 3;
    int which = blockIdx.x >> 2;
    const float* wv = which ? mo_w : re_w;
    const u16* row = xn + (size_t)b * LL * DD;
    float s = 0.f;
    #pragma unroll
    for (int d = 0; d < DD / 64; ++d) s = fmaf(bf2f(row[lane + d * 64]), wv[lane + d * 64], s);
    #pragma unroll
    for (int o = 32; o >= 1; o >>= 1) s += __shfl_xor(s, o);
    if (lane == 0) out[(size_t)VV * BL + which * 4 + b] = s + (which ? mo_b[0] : re_b[0]);
}

// ================================================================ host
extern "C" void kernel_launch(void* const* d_in, const int* in_sizes, int n_in,
                              void* d_out, int out_size, void* d_ws, size_t ws_size,
                              hipStream_t stream) {
    const int*   ids      = (const int*)  d_in[0];
    const int*   typ      = (const int*)  d_in[1];
    const float* ts       = (const float*)d_in[2];
    const int*   amask    = (const int*)  d_in[3];
    const float* tok_emb  = (const float*)d_in[4];
    const float* type_emb = (const float*)d_in[5];
    const float* te_freq  = (const float*)d_in[6];
    const float* te_phase = (const float*)d_in[7];
    const float* te_w     = (const float*)d_in[8];
    const float* te_b     = (const float*)d_in[9];
    const float* m_norm_g = (const float*)d_in[10];
    const float* m_norm_b = (const float*)d_in[11];
    const float* m_in_w   = (const float*)d_in[12];
    const float* m_conv_w = (const float*)d_in[13];
    const float* m_conv_b = (const float*)d_in[14];
    const float* m_xproj  = (const float*)d_in[15];
    const float* m_dt_w   = (const float*)d_in[16];
    const float* m_dt_b   = (const float*)d_in[17];
    const float* m_Alog   = (const float*)d_in[18];
    const float* m_D      = (const float*)d_in[19];
    const float* m_out_w  = (const float*)d_in[20];
    const float* a_norm_g = (const float*)d_in[21];
    const float* a_norm_b = (const float*)d_in[22];
    const float* a_qkv_w  = (const float*)d_in[23];
    const float* a_out_w  = (const float*)d_in[24];
    const float* a_decay  = (const float*)d_in[25];
    const float* a_ffg    = (const float*)d_in[26];
    const float* a_ffb    = (const float*)d_in[27];
    const float* a_ff1    = (const float*)d_in[28];
    const float* a_ff2    = (const float*)d_in[29];
    const float* f_g      = (const float*)d_in[30];
    const float* f_b      = (const float*)d_in[31];
    const float* lm_w     = (const float*)d_in[32];
    const float* re_w     = (const float*)d_in[33];
    const float* re_b     = (const float*)d_in[34];
    const float* mo_w     = (const float*)d_in[35];
    const float* mo_b     = (const float*)d_in[36];

    float* out = (float*)d_out;
    float* ws  = (float*)d_ws;

    // workspace layout (float offsets)
    float* x    = ws;                              // BL*D fp32                (1,048,576)
    u16*   xnb  = (u16*)(ws + 1048576);            // BL*D bf16                (524,288 f)
    float* t1   = ws + 1572864;                    // BL*1024 fp32 xz/qkv; lm_w bf16 at end (4,194,304)
    float* t2   = ws + 5767168;                    // BL*512 fp32 xb           (2,097,152)
    float* b1   = ws + 7864320;                    // bf16 multi: feat/xbb/y/attn-out/ffh (2,097,152)
    float* t3   = ws + 9961472;                    // BL*512 fp32 dt           (2,097,152)
    float* t5   = ws + 12058624;                   // BL*32 fp32 bc            (131,072)
    u16*   wbuf = (u16*)(ws + 12189696);           // all non-lm weights bf16  (2,834,432 f)
    float* sP   = ws + 15024128;                   // nc*B*DI*S
    // sL follows sP

    // scan chunking: use 64 chunks if workspace allows, else 32
    int nc = (ws_size >= (size_t)(15024128 + 2 * 64 * 32768) * 4) ? 64 : 32;
    size_t snc = (size_t)nc * BB * DII / 512 * 32768 / 64;  // nc*32768
    snc = (size_t)nc * 32768;
    float* sL = sP + snc;
    int cln = LL / nc;

    // weight sub-pointers (bf16 offsets in wbuf)
    const u16* w_te  = wbuf;
    const u16* w_qkv = wbuf + 65536;
    const u16* w_ao  = wbuf + 458752;
    const u16* w_ff1 = wbuf + 589824;
    const u16* w_ff2 = wbuf + 1114112;
    const u16* w_min = wbuf + 1638400;
    const u16* w_mo  = wbuf + 3211264;
    const u16* w_dtx = wbuf + 3997696;

    // 0. convert all weights to bf16 (one pass)
    cvtall_k<<<WB_TOT / 1024, 256, 0, stream>>>(
        te_w, a_qkv_w, a_out_w, a_ff1, a_ff2, m_in_w, m_out_w, m_dt_w, m_xproj, wbuf);
    // 1. time features -> b1 (bf16)
    feat_k<<<BL, 256, 0, stream>>>(ts, te_freq, te_phase, (u16*)b1);
    // 2. enc = feat @ te_w^T + te_b -> x (fp32)
    bgemm_k<0, true, false, false><<<dim3(4, BL / 64), 256, 0, stream>>>(
        (u16*)b1, w_te, te_b, nullptr, x, nullptr, BL, DD, DD);
    // 3. x += tok_emb[ids] + type_emb[typ]
    embed_k<<<BL, 256, 0, stream>>>(x, ids, typ, tok_emb, type_emb);

    int mi = 0, ai = 0;
    for (int i = 0; i < 8; ++i) {
        if ((i + 1) % 4 == 0) {
            // ------------- attention block ai
            ln_k<<<BL, 256, 0, stream>>>(x, a_norm_g + ai * DD, a_norm_b + ai * DD, xnb);
            bgemm_k<0, false, false, false><<<dim3(12, BL / 64), 256, 0, stream>>>(
                xnb, w_qkv + (size_t)ai * 196608, nullptr, nullptr, t1, nullptr, BL, 3 * DD, DD);
            fattn_k<<<BB * HH * (LL / 64), 256, 0, stream>>>(
                t1, ts, amask, a_decay + ai * HH, (u16*)b1);
            bgemm_k<0, false, true, false><<<dim3(4, BL / 64), 256, 0, stream>>>(
                (u16*)b1, w_ao + (size_t)ai * 65536, nullptr, x, x, nullptr, BL, DD, DD);
            ln_k<<<BL, 256, 0, stream>>>(x, a_ffg + ai * DD, a_ffb + ai * DD, xnb);
            bgemm_k<1, false, false, true><<<dim3(16, BL / 64), 256, 0, stream>>>(
                xnb, w_ff1 + (size_t)ai * 262144, nullptr, nullptr, b1, nullptr, BL, 4 * DD, DD);
            bgemm_k<0, false, true, false><<<dim3(4, BL / 64), 256, 0, stream>>>(
                (u16*)b1, w_ff2 + (size_t)ai * 262144, nullptr, x, x, nullptr, BL, DD, 4 * DD);
            ++ai;
        } else {
            // ------------- mamba block mi
            ln_k<<<BL, 256, 0, stream>>>(x, m_norm_g + mi * DD, m_norm_b + mi * DD, xnb);
            bgemm_k<0, false, false, false><<<dim3(16, BL / 64), 256, 0, stream>>>(
                xnb, w_min + (size_t)mi * 262144, nullptr, nullptr, t1, nullptr, BL, 2 * DII, DD);
            conv_k<<<(BL * DII) / 256, 256, 0, stream>>>(
                t1, m_conv_w + (size_t)mi * DII * DCC, m_conv_b + mi * DII, t2, (u16*)b1);
            // fused dt (softplus+bias -> t3) + xproj (-> t5), N=544
            bgemm_k<3, false, false, false><<<dim3(9, BL / 64), 256, 0, stream>>>(
                (u16*)b1, w_dtx + (size_t)mi * 278528, m_dt_b + mi * DII, nullptr, t3, t5, BL, 544, DII);
            scanA_k<<<BB * nc * 2, 256, 0, stream>>>(
                t3, t2, t5, m_Alog + (size_t)mi * DII * SS, sP, sL, nc, cln);
            scanB_k<<<8, 256, 0, stream>>>(sP, sL, nc);
            scanC_k<<<BB * nc * 2, 256, 0, stream>>>(
                t3, t2, t5, t1, m_Alog + (size_t)mi * DII * SS, m_D + mi * DII, sL, (u16*)b1, nc, cln);
            bgemm_k<0, false, true, false><<<dim3(4, BL / 64), 256, 0, stream>>>(
                (u16*)b1, w_mo + (size_t)mi * 131072, nullptr, x, x, nullptr, BL, DD, DII);
            ++mi;
        }
    }

    // final layernorm -> xnb (bf16, feeds lm GEMM + heads)
    ln_k<<<BL, 256, 0, stream>>>(x, f_g, f_b, xnb);
    // lm_w -> bf16 into t1 (free now)
    u16* wlm = (u16*)t1;
    cvt_k<<<(VV * DD / 4 + 255) / 256, 256, 0, stream>>>(lm_w, wlm, VV * DD);
    // lm logits -> out[0 : BL*V]   (XCD-chunked MFMA)
    mgemmL_k<<<dim3(32, 256), 256, 0, stream>>>(xnb, wlm, out, BL, VV, DD);
    // readm / mort heads
    heads_k<<<8, 64, 0, stream>>>(xnb, re_w, re_b, mo_w, mo_b, out);
}

// Round 7
// 1414.186 us; speedup vs baseline: 8.8631x; 1.0581x over previous
//
#include <hip/hip_runtime.h>
#include <hip/hip_bf16.h>
#include <math.h>

// Problem constants
#define BB 4
#define LL 1024
#define BL (BB*LL)          // 4096 tokens
#define DD 256
#define VV 32000
#define HH 4
#define DH 64
#define SS 16
#define DCC 4
#define DII 512

typedef float f32x4 __attribute__((ext_vector_type(4)));
typedef short bh8  __attribute__((ext_vector_type(8)));   // 8 bf16 (bit pattern)
typedef unsigned short u16;

__device__ __forceinline__ float sp_f(float x) {        // softplus
    return fmaxf(x, 0.f) + log1pf(expf(-fabsf(x)));
}
__device__ __forceinline__ float silu_f(float x) {
    return x / (1.f + expf(-x));
}
__device__ __forceinline__ short f2bf(float f) {
    __hip_bfloat16 h = __float2bfloat16(f);
    short s; __builtin_memcpy(&s, &h, 2); return s;
}
__device__ __forceinline__ float bf2f(u16 u) {
    unsigned v = ((unsigned)u) << 16;
    float f; __builtin_memcpy(&f, &v, 4); return f;
}

// ---------------------------------------------------------------- all weights fp32->bf16 (one pass, incl lm_w)
// wbuf layout (bf16 elems):
//  te_w    [0,        65536)
//  a_qkv   [65536,    458752)
//  a_out   [458752,   589824)
//  a_ff1   [589824,   1114112)
//  a_ff2   [1114112,  1638400)
//  m_in    [1638400,  3211264)
//  m_out   [3211264,  3997696)
//  m_dtx   [3997696,  5668864)  per layer 278528: rows 0..511 dt_w, 512..543 xproj
#define WB_TOT 5668864
#define LM_TOT 8192000
__global__ void cvtall_k(const float* __restrict__ te_w, const float* __restrict__ a_qkv,
                         const float* __restrict__ a_out, const float* __restrict__ a_ff1,
                         const float* __restrict__ a_ff2, const float* __restrict__ m_in,
                         const float* __restrict__ m_out, const float* __restrict__ m_dt,
                         const float* __restrict__ m_xp, const float* __restrict__ lm,
                         u16* __restrict__ dst, u16* __restrict__ dlm) {
    long i = ((long)blockIdx.x * 256 + threadIdx.x) * 4;
    const float* src; long off; u16* d; long doff;
    if (i >= WB_TOT) {
        long j = i - WB_TOT;
        if (j >= LM_TOT) return;
        src = lm; off = j; d = dlm; doff = j;
    } else {
        d = dst; doff = i;
        if      (i < 65536)   { src = te_w;  off = i; }
        else if (i < 458752)  { src = a_qkv; off = i - 65536; }
        else if (i < 589824)  { src = a_out; off = i - 458752; }
        else if (i < 1114112) { src = a_ff1; off = i - 589824; }
        else if (i < 1638400) { src = a_ff2; off = i - 1114112; }
        else if (i < 3211264) { src = m_in;  off = i - 1638400; }
        else if (i < 3997696) { src = m_out; off = i - 3211264; }
        else {
            long l = i - 3997696;
            int mi = (int)(l / 278528);
            long r = l - (long)mi * 278528;
            if (r < 262144) { src = m_dt + (long)mi * 262144; off = r; }
            else            { src = m_xp + (long)mi * 16384;  off = r - 262144; }
        }
    }
    float4 v = *(const float4*)(src + off);
    ushort4 u;
    u.x = (u16)f2bf(v.x); u.y = (u16)f2bf(v.y);
    u.z = (u16)f2bf(v.z); u.w = (u16)f2bf(v.w);
    *(ushort4*)(d + doff) = u;
}

// ---------------------------------------------------------------- time feat (bf16 out)
__global__ void feat_k(const float* __restrict__ ts, const float* __restrict__ freq,
                       const float* __restrict__ phase, u16* __restrict__ feat) {
    int row = blockIdx.x, t = threadIdx.x;
    float tv = ts[row];
    int d = t & 127;
    float f = sp_f(freq[d]);
    float arg = tv * f + phase[d];
    feat[(size_t)row * DD + t] = (u16)f2bf((t < 128) ? sinf(arg) : cosf(arg));
}

// ---------------------------------------------------------------- layernorm (final only, bf16 out)
__global__ void ln_k(const float* __restrict__ x, const float* __restrict__ g,
                     const float* __restrict__ bbias, u16* __restrict__ out) {
    __shared__ float red[8];
    int row = blockIdx.x, t = threadIdx.x;
    float v = x[(size_t)row * DD + t];
    float s = v;
    #pragma unroll
    for (int o = 32; o >= 1; o >>= 1) s += __shfl_xor(s, o);
    if ((t & 63) == 0) red[t >> 6] = s;
    __syncthreads();
    float mean = (red[0] + red[1] + red[2] + red[3]) * (1.f / 256.f);
    float d = v - mean;
    float s2 = d * d;
    #pragma unroll
    for (int o = 32; o >= 1; o >>= 1) s2 += __shfl_xor(s2, o);
    if ((t & 63) == 0) red[4 + (t >> 6)] = s2;
    __syncthreads();
    float var = (red[4] + red[5] + red[6] + red[7]) * (1.f / 256.f);
    out[(size_t)row * DD + t] = (u16)f2bf(d * rsqrtf(var + 1e-5f) * g[t] + bbias[t]);
}

// ---------------------------------------------------------------- LN-fused 64x64-tile MFMA GEMM (K=256 fixed)
// out = LN(X) @ W^T.  Block computes row stats, builds 64x256 bf16 A-tile in LDS once.
// ACT: 0 none, 1 silu. BOUT: bf16 out. VT: also write V^T copy for cols [512,768).
template <int ACT, bool BOUT, bool VT>
__global__ __launch_bounds__(256) void lngemm_k(
    const float* __restrict__ X, const float* __restrict__ g, const float* __restrict__ bb,
    const u16* __restrict__ W, void* __restrict__ outv, u16* __restrict__ vt,
    int M, int N) {
    __shared__ __align__(16) char Abf[32768];   // 64 rows x 256 bf16, swizzled
    __shared__ __align__(16) char Ws[8192];     // 64 rows x 64 bf16 per k-step
    __shared__ float gs[256], bs[256];
    int tid = threadIdx.x;
    int bm = blockIdx.y * 64, bn = blockIdx.x * 64;
    gs[tid] = g[tid]; bs[tid] = bb[tid];

    int row = tid >> 2, part = tid & 3;
    const float* xr = X + (size_t)(bm + row) * 256 + part * 64;
    float4 vv[16];
    float s = 0.f, sq = 0.f;
    #pragma unroll
    for (int i = 0; i < 16; ++i) {
        vv[i] = *(const float4*)(xr + i * 4);
        s  += vv[i].x + vv[i].y + vv[i].z + vv[i].w;
        sq += vv[i].x * vv[i].x + vv[i].y * vv[i].y + vv[i].z * vv[i].z + vv[i].w * vv[i].w;
    }
    s += __shfl_xor(s, 1);  s += __shfl_xor(s, 2);
    sq += __shfl_xor(sq, 1); sq += __shfl_xor(sq, 2);
    float mean = s * (1.f / 256.f);
    float rstd = rsqrtf(sq * (1.f / 256.f) - mean * mean + 1e-5f);
    __syncthreads();   // gs/bs visible
    #pragma unroll
    for (int i8 = 0; i8 < 8; ++i8) {
        bh8 p;
        #pragma unroll
        for (int j = 0; j < 8; ++j) {
            int e = i8 * 8 + j;
            float v = (j & 3) == 0 ? vv[e >> 2].x : (j & 3) == 1 ? vv[e >> 2].y
                    : (j & 3) == 2 ? vv[e >> 2].z : vv[e >> 2].w;
            int c = part * 64 + e;
            p[j] = f2bf((v - mean) * rstd * gs[c] + bs[c]);
        }
        *(bh8*)(Abf + (unsigned)((row * 512 + part * 128 + i8 * 16) ^ ((row & 7) << 4))) = p;
    }
    __syncthreads();

    int lane = tid & 63, wv = tid >> 6;
    int wm = wv >> 1, wn = wv & 1;
    int ro = lane & 15, kg = lane >> 4;
    f32x4 acc[2][2];
    #pragma unroll
    for (int i = 0; i < 2; ++i)
        #pragma unroll
        for (int j = 0; j < 2; ++j) acc[i][j] = (f32x4){0.f, 0.f, 0.f, 0.f};

    const u16* gw = W + (size_t)(bn + row) * 256 + part * 16;
    bool wvalid = (bn + row) < N;
    unsigned swb = (unsigned)(row * 128 + part * 32);
    unsigned sx  = (unsigned)((row & 7) << 4);
    for (int kk = 0; kk < 256; kk += 64) {
        if (kk) __syncthreads();
        bh8 w0 = {}, w1 = {};
        if (wvalid) { w0 = *(const bh8*)(gw + kk); w1 = *(const bh8*)(gw + kk + 8); }
        *(bh8*)(Ws + (swb ^ sx)) = w0;
        *(bh8*)(Ws + ((swb + 16) ^ sx)) = w1;
        __syncthreads();
        #pragma unroll
        for (int ks = 0; ks < 2; ++ks) {
            bh8 af[2], bf_[2];
            #pragma unroll
            for (int m = 0; m < 2; ++m) {
                int r = wm * 32 + m * 16 + ro;
                af[m] = *(const bh8*)(Abf + (unsigned)((r * 512 + kk * 2 + ks * 64 + kg * 16) ^ ((r & 7) << 4)));
            }
            #pragma unroll
            for (int n = 0; n < 2; ++n) {
                int r = wn * 32 + n * 16 + ro;
                bf_[n] = *(const bh8*)(Ws + (unsigned)((r * 128 + ks * 64 + kg * 16) ^ ((r & 7) << 4)));
            }
            #pragma unroll
            for (int m = 0; m < 2; ++m)
                #pragma unroll
                for (int n = 0; n < 2; ++n)
                    acc[m][n] = __builtin_amdgcn_mfma_f32_16x16x32_bf16(af[m], bf_[n], acc[m][n], 0, 0, 0);
        }
    }

    float* outf = (float*)outv;
    u16*   outb = (u16*)outv;
    int cr = (lane >> 4) * 4, cc = lane & 15;
    #pragma unroll
    for (int mf = 0; mf < 2; ++mf) {
        #pragma unroll
        for (int nf = 0; nf < 2; ++nf) {
            int n = bn + wn * 32 + nf * 16 + cc;
            if (n >= N) continue;
            int mbase = bm + wm * 32 + mf * 16 + cr;
            f32x4 a = acc[mf][nf];
            #pragma unroll
            for (int r = 0; r < 4; ++r) {
                float v = a[r];
                if (ACT == 1) v = silu_f(v);
                if (BOUT) outb[(size_t)(mbase + r) * N + n] = (u16)f2bf(v);
                else      outf[(size_t)(mbase + r) * N + n] = v;
            }
            if (VT && n >= 512) {
                int hh = (n - 512) >> 6, dd = (n - 512) & 63;
                int b_ = mbase >> 10, l = mbase & 1023;
                ushort4 uv;
                uv.x = (u16)f2bf(acc[mf][nf][0]); uv.y = (u16)f2bf(acc[mf][nf][1]);
                uv.z = (u16)f2bf(acc[mf][nf][2]); uv.w = (u16)f2bf(acc[mf][nf][3]);
                *(ushort4*)(vt + ((((size_t)b_ * HH + hh) * DH + dd) << 10) + l) = uv;
            }
        }
    }
}

// ---------------------------------------------------------------- 64x64-tile MFMA GEMM, bf16 A and W
// ACT: 0 none, 1 silu, 3 dtx (n<512: softplus+bias -> outf; else raw -> out2), 4 embed-residual
template <int ACT, bool HASB, bool HASR, bool BOUT>
__global__ __launch_bounds__(256) void bgemm_k(
    const u16* __restrict__ A, const u16* __restrict__ W,
    const float* __restrict__ bias, const float* __restrict__ res,
    void* __restrict__ outv, float* __restrict__ out2, int M, int N, int K,
    const int* __restrict__ ids, const int* __restrict__ typ,
    const float* __restrict__ tok, const float* __restrict__ tpe) {
    __shared__ __align__(16) char lds[16384];
    char* As = lds;
    char* Ws = lds + 8192;
    int tid = threadIdx.x;
    int bm = blockIdx.y * 64, bn = blockIdx.x * 64;
    int row = tid >> 2, q = tid & 3;
    int lane = tid & 63, wv = tid >> 6;
    int wm = wv >> 1, wn = wv & 1;
    int ro = lane & 15, kg = lane >> 4;

    f32x4 acc[2][2];
    #pragma unroll
    for (int i = 0; i < 2; ++i)
        #pragma unroll
        for (int j = 0; j < 2; ++j) acc[i][j] = (f32x4){0.f, 0.f, 0.f, 0.f};

    const u16* ga = A + (size_t)(bm + row) * K + q * 16;
    const u16* gw = W + (size_t)(bn + row) * K + q * 16;
    bool wvalid = (bn + row) < N;
    unsigned swb = (unsigned)(row * 128 + q * 32);
    unsigned sx  = (unsigned)((row & 7) << 4);

    for (int kk = 0; kk < K; kk += 64) {
        if (kk) __syncthreads();
        {
            *(bh8*)(As + (swb ^ sx)) = *(const bh8*)(ga);
            *(bh8*)(As + ((swb + 16) ^ sx)) = *(const bh8*)(ga + 8);
            bh8 w0 = {}, w1 = {};
            if (wvalid) { w0 = *(const bh8*)(gw); w1 = *(const bh8*)(gw + 8); }
            *(bh8*)(Ws + (swb ^ sx)) = w0;
            *(bh8*)(Ws + ((swb + 16) ^ sx)) = w1;
        }
        ga += 64; gw += 64;
        __syncthreads();
        #pragma unroll
        for (int ks = 0; ks < 2; ++ks) {
            bh8 af[2], bf_[2];
            #pragma unroll
            for (int m = 0; m < 2; ++m) {
                int r = wm * 32 + m * 16 + ro;
                af[m] = *(const bh8*)(As + (unsigned)((r * 128 + ks * 64 + kg * 16) ^ ((r & 7) << 4)));
            }
            #pragma unroll
            for (int n = 0; n < 2; ++n) {
                int r = wn * 32 + n * 16 + ro;
                bf_[n] = *(const bh8*)(Ws + (unsigned)((r * 128 + ks * 64 + kg * 16) ^ ((r & 7) << 4)));
            }
            #pragma unroll
            for (int m = 0; m < 2; ++m)
                #pragma unroll
                for (int n = 0; n < 2; ++n)
                    acc[m][n] = __builtin_amdgcn_mfma_f32_16x16x32_bf16(af[m], bf_[n], acc[m][n], 0, 0, 0);
        }
    }

    float* outf = (float*)outv;
    u16*   outb = (u16*)outv;
    int cr = (lane >> 4) * 4, cc = lane & 15;
    #pragma unroll
    for (int mf = 0; mf < 2; ++mf) {
        #pragma unroll
        for (int nf = 0; nf < 2; ++nf) {
            int n = bn + wn * 32 + nf * 16 + cc;
            if (n >= N) continue;
            int mbase = bm + wm * 32 + mf * 16 + cr;
            f32x4 a = acc[mf][nf];
            #pragma unroll
            for (int r = 0; r < 4; ++r) {
                float v = a[r];
                int m = mbase + r;
                if (ACT == 3) {
                    if (n < 512) outf[(size_t)m * 512 + n] = sp_f(v + bias[n]);
                    else         out2[(size_t)m * 32 + (n - 512)] = v;
                } else if (ACT == 4) {
                    v += bias[n] + tok[(size_t)ids[m] * DD + n] + tpe[(size_t)typ[m] * DD + n];
                    outf[(size_t)m * N + n] = v;
                } else {
                    if (HASB) v += bias[n];
                    if (ACT == 1) v = silu_f(v);
                    if (HASR) v += res[(size_t)m * N + n];
                    if (BOUT) outb[(size_t)m * N + n] = (u16)f2bf(v);
                    else      outf[(size_t)m * N + n] = v;
                }
            }
        }
    }
}

// ---------------------------------------------------------------- lm-head GEMM: bf16 A and W, XCD-chunked
__global__ __launch_bounds__(256) void mgemmL_k(
    const u16* __restrict__ A, const u16* __restrict__ W,
    float* __restrict__ out, int M, int N, int K) {
    __shared__ __align__(16) char lds[32768];
    char* As = lds;
    char* Ws = lds + 16384;
    int lid = blockIdx.y * 32 + blockIdx.x;
    int xcd = lid & 7, wk = lid >> 3;
    int nt = xcd * 32 + (wk >> 5);
    int mt = wk & 31;
    if (nt * 128 >= N) return;            // uniform early exit (before any barrier)
    int bm = mt * 128, bn = nt * 128;

    int tid = threadIdx.x;
    int row = tid >> 1, half = tid & 1;
    int lane = tid & 63, wv = tid >> 6;
    int wm = wv >> 1, wn = wv & 1;
    int ro = lane & 15, kg = lane >> 4;

    f32x4 acc[4][4];
    #pragma unroll
    for (int i = 0; i < 4; ++i)
        #pragma unroll
        for (int j = 0; j < 4; ++j) acc[i][j] = (f32x4){0.f, 0.f, 0.f, 0.f};

    const u16* ga = A + (size_t)(bm + row) * K + half * 32;
    const u16* gw = W + (size_t)(bn + row) * K + half * 32;
    unsigned swb = (unsigned)(row * 128 + half * 64);
    unsigned sx  = (unsigned)((row & 7) << 4);

    for (int kk = 0; kk < K; kk += 64) {
        if (kk) __syncthreads();
        #pragma unroll
        for (int j = 0; j < 4; ++j) {
            *(bh8*)(As + ((swb + j * 16) ^ sx)) = *(const bh8*)(ga + j * 8);
            *(bh8*)(Ws + ((swb + j * 16) ^ sx)) = *(const bh8*)(gw + j * 8);
        }
        ga += 64; gw += 64;
        __syncthreads();
        #pragma unroll
        for (int ks = 0; ks < 2; ++ks) {
            bh8 af[4], bf_[4];
            #pragma unroll
            for (int m = 0; m < 4; ++m) {
                int r = wm * 64 + m * 16 + ro;
                af[m] = *(const bh8*)(As + (unsigned)((r * 128 + ks * 64 + kg * 16) ^ ((r & 7) << 4)));
            }
            #pragma unroll
            for (int n = 0; n < 4; ++n) {
                int r = wn * 64 + n * 16 + ro;
                bf_[n] = *(const bh8*)(Ws + (unsigned)((r * 128 + ks * 64 + kg * 16) ^ ((r & 7) << 4)));
            }
            #pragma unroll
            for (int m = 0; m < 4; ++m)
                #pragma unroll
                for (int n = 0; n < 4; ++n)
                    acc[m][n] = __builtin_amdgcn_mfma_f32_16x16x32_bf16(af[m], bf_[n], acc[m][n], 0, 0, 0);
        }
    }

    int cr = (lane >> 4) * 4, cc = lane & 15;
    #pragma unroll
    for (int mf = 0; mf < 4; ++mf) {
        #pragma unroll
        for (int nf = 0; nf < 4; ++nf) {
            int n = bn + wn * 64 + nf * 16 + cc;
            int mbase = bm + wm * 64 + mf * 16 + cr;
            f32x4 a = acc[mf][nf];
            #pragma unroll
            for (int r = 0; r < 4; ++r)
                out[(size_t)(mbase + r) * N + n] = a[r];
        }
    }
}

// ---------------------------------------------------------------- depthwise causal conv + silu (bf16 in/out)
__global__ void conv_k(const u16* __restrict__ xz, const float* __restrict__ w,
                       const float* __restrict__ cb, u16* __restrict__ xbb) {
    int idx = blockIdx.x * blockDim.x + threadIdx.x;  // BL*DI
    int c = idx & (DII - 1);
    int row = idx >> 9;
    int l = row & (LL - 1);
    int base = row - l;
    const float* wc = w + c * DCC;
    float s = cb[c];
    #pragma unroll
    for (int j = 0; j < DCC; ++j) {
        int ll = l - (DCC - 1) + j;
        if (ll >= 0) s = fmaf(wc[j], bf2f(xz[((size_t)(base + ll)) * (2 * DII) + c]), s);
    }
    xbb[(size_t)idx] = (u16)f2bf(silu_f(s));
}

// ---------------------------------------------------------------- chunked selective scan (A + C w/ fused prefix)
__global__ __launch_bounds__(256) void scanA_k(
    const float* __restrict__ dt, const u16* __restrict__ xb,
    const float* __restrict__ bc, const float* __restrict__ Alog,
    float* __restrict__ P, float* __restrict__ Lc, int nc, int cln) {
    int bid = blockIdx.x;
    int per_b = nc * 2;
    int b = bid / per_b;
    int rem = bid - b * per_b;
    int c = rem >> 1;
    int di = (rem & 1) * 256 + threadIdx.x;
    float A[SS], ap[SS], h[SS];
    #pragma unroll
    for (int s = 0; s < SS; ++s) { A[s] = -expf(Alog[di * SS + s]); ap[s] = 1.f; h[s] = 0.f; }
    for (int l = c * cln; l < c * cln + cln; ++l) {
        size_t base = (size_t)b * LL + l;
        float dtv = dt[base * DII + di];
        float xv  = bf2f(xb[base * DII + di]);
        const float* Bt = bc + base * (2 * SS);
        float u = dtv * xv;
        #pragma unroll
        for (int s = 0; s < SS; ++s) {
            float a = expf(dtv * A[s]);
            ap[s] *= a;
            h[s] = fmaf(a, h[s], u * Bt[s]);
        }
    }
    size_t o = (((size_t)c * BB + b) * DII + di) * SS;
    #pragma unroll
    for (int j = 0; j < 4; ++j) {
        *(f32x4*)(P  + o + j * 4) = (f32x4){ap[j*4], ap[j*4+1], ap[j*4+2], ap[j*4+3]};
        *(f32x4*)(Lc + o + j * 4) = (f32x4){h[j*4],  h[j*4+1],  h[j*4+2],  h[j*4+3]};
    }
}

__global__ __launch_bounds__(256) void scanC_k(
    const float* __restrict__ dt, const u16* __restrict__ xb,
    const float* __restrict__ bc, const u16* __restrict__ xz,
    const float* __restrict__ Alog, const float* __restrict__ Dp,
    const float* __restrict__ P, const float* __restrict__ Lc,
    u16* __restrict__ y, int nc, int cln) {
    int bid = blockIdx.x;
    int per_b = nc * 2;
    int b = bid / per_b;
    int rem = bid - b * per_b;
    int c = rem >> 1;
    int di = (rem & 1) * 256 + threadIdx.x;
    float A[SS];
    #pragma unroll
    for (int s = 0; s < SS; ++s) A[s] = -expf(Alog[di * SS + s]);
    // fused prefix: h_init = scan of (P,Lc) over chunks < c
    f32x4 h4[4];
    #pragma unroll
    for (int j = 0; j < 4; ++j) h4[j] = (f32x4){0.f, 0.f, 0.f, 0.f};
    for (int cc = 0; cc < c; ++cc) {
        size_t o = (((size_t)cc * BB + b) * DII + di) * SS;
        #pragma unroll
        for (int j = 0; j < 4; ++j) {
            f32x4 p  = *(const f32x4*)(P  + o + j * 4);
            f32x4 lc = *(const f32x4*)(Lc + o + j * 4);
            h4[j] = p * h4[j] + lc;
        }
    }
    float h[SS];
    #pragma unroll
    for (int j = 0; j < 4; ++j) {
        h[j*4+0] = h4[j][0]; h[j*4+1] = h4[j][1]; h[j*4+2] = h4[j][2]; h[j*4+3] = h4[j][3];
    }
    float Dv = Dp[di];
    for (int l = c * cln; l < c * cln + cln; ++l) {
        size_t base = (size_t)b * LL + l;
        float dtv = dt[base * DII + di];
        float xv  = bf2f(xb[base * DII + di]);
        float zv  = bf2f(xz[base * (2 * DII) + DII + di]);
        const float* Bt = bc + base * (2 * SS);
        float u = dtv * xv;
        float acc = 0.f;
        #pragma unroll
        for (int s = 0; s < SS; ++s) {
            float a = expf(dtv * A[s]);
            h[s] = fmaf(a, h[s], u * Bt[s]);
            acc = fmaf(h[s], Bt[SS + s], acc);
        }
        y[base * DII + di] = (u16)f2bf(fmaf(Dv, xv, acc) * silu_f(zv));
    }
}

// ---------------------------------------------------------------- flash attention (MFMA), bf16 qkv + V^T in
__global__ __launch_bounds__(256) void fattn_k(
    const u16* __restrict__ qkv, const u16* __restrict__ vt,
    const float* __restrict__ ts, const int* __restrict__ mask,
    const float* __restrict__ decay, u16* __restrict__ out) {
    __shared__ __align__(16) char ksm[8192];
    __shared__ __align__(16) char vsm[8192];
    __shared__ __align__(16) char psm[8192];
    __shared__ float tsk[64];
    __shared__ int   msk[64];

    int tid = threadIdx.x;
    int lane = tid & 63, wvi = tid >> 6;
    int qt = blockIdx.x & 15;
    int h  = (blockIdx.x >> 4) & 3;
    int b  = blockIdx.x >> 6;
    int q0 = qt * 64;
    int g = lane >> 4, c = lane & 15;

    bh8 qf[2];
    {
        const u16* qrow = qkv + ((size_t)(b * LL + q0 + wvi * 16 + c)) * (3 * DD) + h * DH;
        qf[0] = *(const bh8*)(qrow + g * 8);
        qf[1] = *(const bh8*)(qrow + 32 + g * 8);
    }
    float tq[4];
    #pragma unroll
    for (int j = 0; j < 4; ++j) tq[j] = ts[b * LL + q0 + wvi * 16 + g * 4 + j];
    float spd = sp_f(decay[h]);

    f32x4 o[4];
    #pragma unroll
    for (int n = 0; n < 4; ++n) o[n] = (f32x4){0.f, 0.f, 0.f, 0.f};
    float mrow[4] = {-INFINITY, -INFINITY, -INFINITY, -INFINITY};
    float drow[4] = {0.f, 0.f, 0.f, 0.f};

    char* pw = psm + wvi * 2048;

    for (int kt = 0; kt <= qt; ++kt) {
        int k0 = kt * 64;
        __syncthreads();
        {
            int row = tid >> 2, qq = tid & 3;
            unsigned sw = (unsigned)((row & 7) << 4);
            unsigned base = (unsigned)(row * 128 + qq * 32);
            const u16* kr = qkv + ((size_t)(b * LL + k0 + row)) * (3 * DD) + DD + h * DH + qq * 16;
            *(bh8*)(ksm + (base ^ sw)) = *(const bh8*)(kr);
            *(bh8*)(ksm + ((base + 16) ^ sw)) = *(const bh8*)(kr + 8);
            const u16* vr = vt + ((((size_t)b * HH + h) * DH + row) << 10) + k0 + qq * 16;
            *(bh8*)(vsm + (base ^ sw)) = *(const bh8*)(vr);
            *(bh8*)(vsm + ((base + 16) ^ sw)) = *(const bh8*)(vr + 8);
            if (tid < 64) { tsk[tid] = ts[b * LL + k0 + tid]; msk[tid] = mask[b * LL + k0 + tid]; }
        }
        __syncthreads();

        f32x4 sf[4];
        #pragma unroll
        for (int n = 0; n < 4; ++n) sf[n] = (f32x4){0.f, 0.f, 0.f, 0.f};
        #pragma unroll
        for (int ks = 0; ks < 2; ++ks) {
            #pragma unroll
            for (int nf = 0; nf < 4; ++nf) {
                int rr = nf * 16 + c;
                bh8 kf = *(const bh8*)(ksm + (unsigned)((rr * 128 + ks * 64 + g * 16) ^ ((rr & 7) << 4)));
                sf[nf] = __builtin_amdgcn_mfma_f32_16x16x32_bf16(qf[ks], kf, sf[nf], 0, 0, 0);
            }
        }
        float mnew[4] = {mrow[0], mrow[1], mrow[2], mrow[3]};
        #pragma unroll
        for (int nf = 0; nf < 4; ++nf) {
            int kk = c + 16 * nf;
            float tk = tsk[kk];
            bool md = (msk[kk] == 0);
            #pragma unroll
            for (int j = 0; j < 4; ++j) {
                int qrow = q0 + wvi * 16 + g * 4 + j;
                float s = sf[nf][j] * 0.125f - spd * fabsf(tq[j] - tk) * (1.f / 24.f);
                bool dead = md || (k0 + kk > qrow);
                s = dead ? -INFINITY : s;
                sf[nf][j] = s;
                mnew[j] = fmaxf(mnew[j], s);
            }
        }
        #pragma unroll
        for (int off = 1; off <= 8; off <<= 1)
            #pragma unroll
            for (int j = 0; j < 4; ++j) mnew[j] = fmaxf(mnew[j], __shfl_xor(mnew[j], off));
        float scl[4], psum[4];
        #pragma unroll
        for (int j = 0; j < 4; ++j) {
            scl[j] = (mnew[j] == -INFINITY) ? 1.f : expf(mrow[j] - mnew[j]);
            psum[j] = 0.f;
            mrow[j] = mnew[j];
        }
        #pragma unroll
        for (int nf = 0; nf < 4; ++nf) {
            #pragma unroll
            for (int j = 0; j < 4; ++j) {
                float s = sf[nf][j];
                float p = (s == -INFINITY) ? 0.f : expf(s - mrow[j]);
                psum[j] += p;
                int row = g * 4 + j;
                *(short*)(pw + (unsigned)((row * 128 + (c + 16 * nf) * 2) ^ ((row & 7) << 4))) = f2bf(p);
            }
        }
        #pragma unroll
        for (int off = 1; off <= 8; off <<= 1)
            #pragma unroll
            for (int j = 0; j < 4; ++j) psum[j] += __shfl_xor(psum[j], off);
        #pragma unroll
        for (int j = 0; j < 4; ++j) drow[j] = drow[j] * scl[j] + psum[j];
        #pragma unroll
        for (int n = 0; n < 4; ++n)
            #pragma unroll
            for (int j = 0; j < 4; ++j) o[n][j] *= scl[j];
        #pragma unroll
        for (int ks = 0; ks < 2; ++ks) {
            bh8 pf = *(const bh8*)(pw + (unsigned)((c * 128 + ks * 64 + g * 16) ^ ((c & 7) << 4)));
            #pragma unroll
            for (int n = 0; n < 4; ++n) {
                int rr = n * 16 + c;
                bh8 vf = *(const bh8*)(vsm + (unsigned)((rr * 128 + ks * 64 + g * 16) ^ ((rr & 7) << 4)));
                o[n] = __builtin_amdgcn_mfma_f32_16x16x32_bf16(pf, vf, o[n], 0, 0, 0);
            }
        }
    }
    #pragma unroll
    for (int n = 0; n < 4; ++n) {
        #pragma unroll
        for (int j = 0; j < 4; ++j) {
            int qrow = q0 + wvi * 16 + g * 4 + j;
            out[((size_t)(b * LL + qrow)) * DD + h * DH + c + 16 * n] = (u16)f2bf(o[n][j] / drow[j]);
        }
    }
}

// ---------------------------------------------------------------- readm / mort heads (bf16 xn)
__global__ __launch_bounds__(64) void heads_k(
    const u16* __restrict__ xn, const float* __restrict__ re_w, const float* __restrict__ re_b,
    const float* __restrict__ mo_w, const float* __restrict__ mo_b, float* __restrict__ out) {
    int lane = threadIdx.x;
    int b = blockIdx.x & 3;
    int which = blockIdx.x >> 2;
    const float* wv = which ? mo_w : re_w;
    const u16* row = xn + (size_t)b * LL * DD;
    float s = 0.f;
    #pragma unroll
    for (int d = 0; d < DD / 64; ++d) s = fmaf(bf2f(row[lane + d * 64]), wv[lane + d * 64], s);
    #pragma unroll
    for (int o = 32; o >= 1; o >>= 1) s += __shfl_xor(s, o);
    if (lane == 0) out[(size_t)VV * BL + which * 4 + b] = s + (which ? mo_b[0] : re_b[0]);
}

// ================================================================ host
extern "C" void kernel_launch(void* const* d_in, const int* in_sizes, int n_in,
                              void* d_out, int out_size, void* d_ws, size_t ws_size,
                              hipStream_t stream) {
    const int*   ids      = (const int*)  d_in[0];
    const int*   typ      = (const int*)  d_in[1];
    const float* ts       = (const float*)d_in[2];
    const int*   amask    = (const int*)  d_in[3];
    const float* tok_emb  = (const float*)d_in[4];
    const float* type_emb = (const float*)d_in[5];
    const float* te_freq  = (const float*)d_in[6];
    const float* te_phase = (const float*)d_in[7];
    const float* te_w     = (const float*)d_in[8];
    const float* te_b     = (const float*)d_in[9];
    const float* m_norm_g = (const float*)d_in[10];
    const float* m_norm_b = (const float*)d_in[11];
    const float* m_in_w   = (const float*)d_in[12];
    const float* m_conv_w = (const float*)d_in[13];
    const float* m_conv_b = (const float*)d_in[14];
    const float* m_xproj  = (const float*)d_in[15];
    const float* m_dt_w   = (const float*)d_in[16];
    const float* m_dt_b   = (const float*)d_in[17];
    const float* m_Alog   = (const float*)d_in[18];
    const float* m_D      = (const float*)d_in[19];
    const float* m_out_w  = (const float*)d_in[20];
    const float* a_norm_g = (const float*)d_in[21];
    const float* a_norm_b = (const float*)d_in[22];
    const float* a_qkv_w  = (const float*)d_in[23];
    const float* a_out_w  = (const float*)d_in[24];
    const float* a_decay  = (const float*)d_in[25];
    const float* a_ffg    = (const float*)d_in[26];
    const float* a_ffb    = (const float*)d_in[27];
    const float* a_ff1    = (const float*)d_in[28];
    const float* a_ff2    = (const float*)d_in[29];
    const float* f_g      = (const float*)d_in[30];
    const float* f_b      = (const float*)d_in[31];
    const float* lm_w     = (const float*)d_in[32];
    const float* re_w     = (const float*)d_in[33];
    const float* re_b     = (const float*)d_in[34];
    const float* mo_w     = (const float*)d_in[35];
    const float* mo_b     = (const float*)d_in[36];

    float* out = (float*)d_out;
    float* ws  = (float*)d_ws;

    // workspace layout (float offsets) — sizes in floats:
    //  x    @ 0          1,048,576   (BL*D fp32)
    //  xnb  @ 1,048,576    524,288   (BL*D bf16)
    //  t1   @ 1,572,864  2,097,152   (BL*1024 bf16 xz/qkv)
    //  b1   @ 3,670,016  2,097,152   (BL*1024 bf16 multi)
    //  b2   @ 5,767,168  1,048,576   (BL*512 bf16 y)
    //  t3   @ 6,815,744  2,097,152   (BL*512 fp32 dt)
    //  t5   @ 8,912,896    131,072   (BL*32 fp32 bc)
    //  vtb  @ 9,043,968    524,288   (B*H*DH*L bf16 = 1,048,576 u16)  [was 4x too small -> NaN]
    //  wbuf @ 9,568,256  2,834,432   (non-lm weights bf16)
    //  wlm  @ 12,402,688 4,096,000   (lm_w bf16 = 8,192,000 u16)      [was 2x too small]
    //  sP   @ 16,498,688 nc*32,768
    //  sL   = sP + nc*32,768
    float* x    = ws;
    u16*   xnb  = (u16*)(ws + 1048576);
    u16*   t1   = (u16*)(ws + 1572864);
    u16*   b1   = (u16*)(ws + 3670016);
    u16*   b2   = (u16*)(ws + 5767168);
    float* t3   = ws + 6815744;
    float* t5   = ws + 8912896;
    u16*   vtb  = (u16*)(ws + 9043968);
    u16*   wbuf = (u16*)(ws + 9568256);
    u16*   wlm  = (u16*)(ws + 12402688);
    float* sP   = ws + 16498688;
    int nc = (ws_size >= (size_t)(16498688 + 2 * 64 * 32768) * 4) ? 64 : 32;
    float* sL = sP + (size_t)nc * 32768;
    int cln = LL / nc;

    const u16* w_te  = wbuf;
    const u16* w_qkv = wbuf + 65536;
    const u16* w_ao  = wbuf + 458752;
    const u16* w_ff1 = wbuf + 589824;
    const u16* w_ff2 = wbuf + 1114112;
    const u16* w_min = wbuf + 1638400;
    const u16* w_mo  = wbuf + 3211264;
    const u16* w_dtx = wbuf + 3997696;

    // 0. convert all weights (incl lm_w) to bf16
    cvtall_k<<<(WB_TOT + LM_TOT) / 1024, 256, 0, stream>>>(
        te_w, a_qkv_w, a_out_w, a_ff1, a_ff2, m_in_w, m_out_w, m_dt_w, m_xproj, lm_w, wbuf, wlm);
    // 1. time features -> b1 (bf16)
    feat_k<<<BL, 256, 0, stream>>>(ts, te_freq, te_phase, b1);
    // 2. x = feat @ te_w^T + te_b + tok_emb[ids] + type_emb[typ]   (embed fused)
    bgemm_k<4, true, false, false><<<dim3(4, BL / 64), 256, 0, stream>>>(
        b1, w_te, te_b, nullptr, x, nullptr, BL, DD, DD, ids, typ, tok_emb, type_emb);

    int mi = 0, ai = 0;
    for (int i = 0; i < 8; ++i) {
        if ((i + 1) % 4 == 0) {
            // ------------- attention block ai
            lngemm_k<0, true, true><<<dim3(12, BL / 64), 256, 0, stream>>>(
                x, a_norm_g + ai * DD, a_norm_b + ai * DD,
                w_qkv + (size_t)ai * 196608, t1, vtb, BL, 3 * DD);
            fattn_k<<<BB * HH * (LL / 64), 256, 0, stream>>>(
                t1, vtb, ts, amask, a_decay + ai * HH, b1);
            bgemm_k<0, false, true, false><<<dim3(4, BL / 64), 256, 0, stream>>>(
                b1, w_ao + (size_t)ai * 65536, nullptr, x, x, nullptr, BL, DD, DD,
                nullptr, nullptr, nullptr, nullptr);
            lngemm_k<1, true, false><<<dim3(16, BL / 64), 256, 0, stream>>>(
                x, a_ffg + ai * DD, a_ffb + ai * DD,
                w_ff1 + (size_t)ai * 262144, b1, nullptr, BL, 4 * DD);
            bgemm_k<0, false, true, false><<<dim3(4, BL / 64), 256, 0, stream>>>(
                b1, w_ff2 + (size_t)ai * 262144, nullptr, x, x, nullptr, BL, DD, 4 * DD,
                nullptr, nullptr, nullptr, nullptr);
            ++ai;
        } else {
            // ------------- mamba block mi
            lngemm_k<0, true, false><<<dim3(16, BL / 64), 256, 0, stream>>>(
                x, m_norm_g + mi * DD, m_norm_b + mi * DD,
                w_min + (size_t)mi * 262144, t1, nullptr, BL, 2 * DII);
            conv_k<<<(BL * DII) / 256, 256, 0, stream>>>(
                t1, m_conv_w + (size_t)mi * DII * DCC, m_conv_b + mi * DII, b1);
            bgemm_k<3, true, false, false><<<dim3(9, BL / 64), 256, 0, stream>>>(
                b1, w_dtx + (size_t)mi * 278528, m_dt_b + mi * DII, nullptr, t3, t5, BL, 544, DII,
                nullptr, nullptr, nullptr, nullptr);
            scanA_k<<<BB * nc * 2, 256, 0, stream>>>(
                t3, b1, t5, m_Alog + (size_t)mi * DII * SS, sP, sL, nc, cln);
            scanC_k<<<BB * nc * 2, 256, 0, stream>>>(
                t3, b1, t5, t1, m_Alog + (size_t)mi * DII * SS, m_D + mi * DII, sP, sL, b2, nc, cln);
            bgemm_k<0, false, true, false><<<dim3(4, BL / 64), 256, 0, stream>>>(
                b2, w_mo + (size_t)mi * 131072, nullptr, x, x, nullptr, BL, DD, DII,
                nullptr, nullptr, nullptr, nullptr);
            ++mi;
        }
    }

    // final layernorm -> xnb (bf16, feeds lm GEMM + heads)
    ln_k<<<BL, 256, 0, stream>>>(x, f_g, f_b, xnb);
    // lm logits -> out[0 : BL*V]   (XCD-chunked MFMA)
    mgemmL_k<<<dim3(32, 256), 256, 0, stream>>>(xnb, wlm, out, BL, VV, DD);
    // readm / mort heads
    heads_k<<<8, 64, 0, stream>>>(xnb, re_w, re_b, mo_w, mo_b, out);
}